// Round 7
// baseline (11091.259 us; speedup 1.0000x reference)
//
#include <hip/hip_runtime.h>

// DeepHandwritingPredictionModel: 3-layer peephole LSTM (B=64,T=800,U=400) + MDN(M=20)
// Round 7 = Round 6 with the pre-staging tc precedence bug fixed.
//  - 30 rec blocks (3 layers x 2 group-pairs x 5 slices), each runs groups g0,g1
//    in alternating phases: g0's LLC commit hides under g1's compute.
//  - in-register LSTM epilogue (operand-swapped MFMA), 1 barrier per phase.
//  - hx[slot][u][b] tagged dwords: producer stores = 64 consecutive dwords/wave.
//  - 20 pre blocks (2 layers x 2 gpairs x 5 splits), 2 timesteps x 2 groups per iter.

#define TSTEPS 800
#define NG 4            // batch groups
#define GB 16           // batches per group
#define NSL 5           // slices / splits per (layer,group)
#define UB 80           // units per slice
#define CB 320          // cols per slice (4 gates * UB)
#define KP 416          // padded K (400 h | 3 x | 1 one | pad)
#define RD 16           // hring / zin ring depth
#define HXD 4           // tagged hx ring depth
#define AS 424          // A LDS stride (bf16)

typedef __attribute__((ext_vector_type(8))) __bf16 bf16x8;
typedef __attribute__((ext_vector_type(4))) float floatx4;

struct Peeps { const float* pi[3]; const float* pf[3]; const float* po[3]; };

__device__ __forceinline__ unsigned short f2bf(float f) {
    unsigned int u = __float_as_uint(f);
    return (unsigned short)((u + 0x7FFFu + ((u >> 16) & 1u)) >> 16);
}
__device__ __forceinline__ float bf_lo(unsigned u) { return __uint_as_float(u << 16); }
__device__ __forceinline__ float bf_hi(unsigned u) { return __uint_as_float(u & 0xFFFF0000u); }
__device__ __forceinline__ float sigm_(float v) { return 1.f / (1.f + __expf(-v)); }
__device__ __forceinline__ float tanh_(float v) { float e = __expf(2.f * v); return 1.f - 2.f / (e + 1.f); }
__device__ __forceinline__ unsigned ld_a(const unsigned* p) {
    return __hip_atomic_load(p, __ATOMIC_RELAXED, __HIP_MEMORY_SCOPE_AGENT);
}
__device__ __forceinline__ unsigned long long ld_a64(const unsigned long long* p) {
    return __hip_atomic_load(p, __ATOMIC_RELAXED, __HIP_MEMORY_SCOPE_AGENT);
}
__device__ __forceinline__ void st_a(unsigned* p, unsigned v) {
    __hip_atomic_store(p, v, __ATOMIC_RELAXED, __HIP_MEMORY_SCOPE_AGENT);
}

// ---- weight packing ------------------------------------------------------
__global__ void pack_rec(const float* __restrict__ Wx, const float* __restrict__ Wh,
                         const float* __restrict__ bias, unsigned short* __restrict__ dst,
                         int is_l0) {
    int idx = blockIdx.x * 256 + threadIdx.x;
    if (idx >= 1600 * KP) return;
    int col = idx / KP, k = idx - col * KP;
    int co = (col & 3) * 400 + (col >> 2);
    float v = 0.f;
    if (k < 400) v = Wh[k * 1600 + co];
    else if (is_l0) {
        if (k < 403) v = Wx[(k - 400) * 1600 + co];
        else if (k == 403) v = bias[co];
    }
    dst[idx] = f2bf(v);
}
__global__ void pack_pre(const float* __restrict__ Wx, const float* __restrict__ bias,
                         unsigned short* __restrict__ dst) {
    int idx = blockIdx.x * 256 + threadIdx.x;
    if (idx >= 1600 * KP) return;
    int col = idx / KP, k = idx - col * KP;
    int co = (col & 3) * 400 + (col >> 2);
    float v = 0.f;
    if (k < 400) v = Wx[(3 + k) * 1600 + co];
    else if (k < 403) v = Wx[(k - 400) * 1600 + co];
    else if (k == 403) v = bias[co];
    dst[idx] = f2bf(v);
}
__global__ void pack_x(const float* __restrict__ x, unsigned short* __restrict__ xp) {
    int idx = blockIdx.x * 256 + threadIdx.x;   // idx = t*64 + b
    if (idx >= TSTEPS * 64) return;
    int t = idx / 64, b = idx - t * 64;
    unsigned short o[4];
    for (int d = 0; d < 3; ++d) o[d] = f2bf(x[(b * TSTEPS + t) * 3 + d]);
    o[3] = 0x3F80u;
    *(uint2*)(xp + (size_t)idx * 4) = *(uint2*)o;
}
__global__ void pack_mdn(const float* __restrict__ Wm, const float* __restrict__ bm,
                         unsigned short* __restrict__ dst) {
    int idx = blockIdx.x * 256 + threadIdx.x;
    if (idx >= 128 * KP) return;
    int col = idx / KP, k = idx - col * KP;
    float v = 0.f;
    if (col < 121) {
        if (k < 400) v = Wm[k * 121 + col];
        else if (k == 400) v = bm[col];
    }
    dst[idx] = f2bf(v);
}

// ---- fused pipeline ------------------------------------------------------
// grid 50 x 640: bid<30 rec (l=bid/10, gp=(bid%10)/5, s=bid%5); else pre.
// hx   : [3][NG][HXD][400][16] u32 tagged (t<<16|bf16), slot t&3
// hring: [3][NG][RD][200][16] u32 packed 2xbf16, slot t&15 (for pre)
// zin  : [2][NG][RD][400][16] u64 (4 gates as 4xbf16), slot t&15
// seqb : FH[(l*NG+g)*NSL+s]*16 ; FZ at +60*16: [(lz*NG+g)*NSL+sp]*16
__global__ __launch_bounds__(640)
void fused_scan(const unsigned short* __restrict__ Bp,
                const unsigned short* __restrict__ Bpre,
                const unsigned short* __restrict__ xpack,
                unsigned* __restrict__ hx,
                unsigned* __restrict__ hring,
                unsigned* __restrict__ zin,
                unsigned* __restrict__ seqb,
                unsigned* __restrict__ h2,      // [T][64][200] dwords (2xbf16)
                Peeps pp) {
    const int tid = threadIdx.x;
    const int lane = tid & 63;
    const int w = tid >> 6;
    const int bid = blockIdx.x;

    __shared__ unsigned short A[4 * 16 * AS];   // rec: [grp][buf][16][AS]; pre: [grp][32][AS]

    for (int i = tid; i < 4 * 16 * AS; i += 640) A[i] = 0;

    const int bs = tid & 15;          // staging batch
    const int ms = tid >> 4;          // staging unit-index 0..39
    const int aoff = (lane & 15) * AS + ((lane >> 4) << 3);
    const int b = lane & 15;          // epilogue batch
    const int q = lane >> 4;          // epilogue unit-within-8 (0..3)

    if (bid < 30) {
        // ---------------- recurrence block (2 groups) ----------------
        const int l = bid / 10;
        const int gp = (bid % 10) / 5;
        const int s = bid % 5;
        bf16x8 breg[2][13];
        #pragma unroll
        for (int n = 0; n < 2; ++n) {
            const unsigned short* bpp = Bp + (size_t)l * 1600 * KP
                + (size_t)(s * CB + w * 32 + n * 16 + b) * KP + (q << 3);
            #pragma unroll
            for (int kt = 0; kt < 13; ++kt) breg[n][kt] = *(const bf16x8*)(bpp + kt * 32);
        }
        // poll mapping: 8 peer-units per thread (u-major coalesced)
        int offs[8], us[8];
        #pragma unroll
        for (int j = 0; j < 8; ++j) {
            int m = ms + 40 * j;
            int u = m + (m >= s * UB ? UB : 0);
            us[j] = u; offs[j] = u * 16 + bs;
        }
        unsigned* hxG[2]; unsigned* ringG[2]; const unsigned long long* zinG[2];
        unsigned* FHownG[2]; const unsigned* FZupG[2]; const unsigned* FZdnG[2];
        #pragma unroll
        for (int gi = 0; gi < 2; ++gi) {
            int g = gp * 2 + gi;
            hxG[gi] = hx + (size_t)(l * NG + g) * HXD * 6400;
            ringG[gi] = hring + (size_t)(l * NG + g) * RD * 3200;
            zinG[gi] = (const unsigned long long*)(zin + (size_t)((l - 1) * NG + g) * RD * 12800);
            FHownG[gi] = seqb + ((l * NG + g) * NSL + s) * 16;
            FZupG[gi] = seqb + (60 + ((l - 1) * NG + g) * NSL) * 16;
            FZdnG[gi] = seqb + (60 + (l * NG + g) * NSL) * 16;
        }
        const int ugA = s * UB + w * 8 + q;
        const int ugB = ugA + 4;
        const int u2A = s * 40 + w * 4 + (q >> 1);
        const float piA = pp.pi[l][ugA], pfA = pp.pf[l][ugA], poA = pp.po[l][ugA];
        const float piB = pp.pi[l][ugB], pfB = pp.pf[l][ugB], poB = pp.po[l][ugB];
        float cA[2] = {0.f, 0.f}, cB[2] = {0.f, 0.f};
        __syncthreads();

        for (int t = 0; t < TSTEPS; ++t) {
            #pragma unroll
            for (int gi = 0; gi < 2; ++gi) {
                const int g = gp * 2 + gi;
                unsigned short* bufC = A + ((gi << 1) | (t & 1)) * (16 * AS);
                unsigned short* bufN = A + ((gi << 1) | ((t + 1) & 1)) * (16 * AS);
                // ---- poll peers' tagged h(t-1) + amortized flag gates ----
                {
                    const unsigned want = (unsigned)(t - 1) << 16;
                    const unsigned* hb = hxG[gi] + (size_t)((t + 3) & 3) * 6400;
                    const unsigned* fp = nullptr; unsigned fneed = 0;
                    if (l > 0 && (t & 3) == 0 && tid < NSL) { fp = FZupG[gi] + tid * 16; fneed = (unsigned)(t + 4); }
                    else if (l < 2 && (t & 7) == 0 && tid >= NSL && tid < 2 * NSL) {
                        fp = FZdnG[gi] + (tid - NSL) * 16; fneed = (unsigned)(t > 8 ? t - 8 : 0);
                    }
                    unsigned v[8];
                    for (;;) {
                        bool ok = true;
                        if (t > 0) {
                            #pragma unroll
                            for (int j = 0; j < 8; ++j) {
                                v[j] = ld_a(hb + offs[j]);
                                ok &= ((v[j] & 0xFFFF0000u) == want);
                            }
                        }
                        if (fp) ok &= (ld_a(fp) >= fneed);
                        if (__all(ok)) break;
                    }
                    if (t > 0) {
                        #pragma unroll
                        for (int j = 0; j < 8; ++j)
                            bufC[bs * AS + us[j]] = (unsigned short)v[j];
                    }
                }
                if (l == 0 && tid < 16)
                    *(uint2*)(&bufC[tid * AS + 400]) = *(const uint2*)(xpack + ((size_t)t * 64 + g * 16 + tid) * 4);
                __syncthreads();                          // B1 (one barrier per phase)
                if (tid == 0) st_a(FHownG[gi], (unsigned)t);

                unsigned long long zuA = 0, zuB = 0;
                if (l > 0) {                              // latency hidden under MFMA
                    const unsigned long long* zp = zinG[gi] + (size_t)(t & 15) * 6400 + b;
                    zuA = ld_a64(zp + ugA * 16);
                    zuB = ld_a64(zp + ugB * 16);
                }

                floatx4 a0 = {0, 0, 0, 0}, a1 = {0, 0, 0, 0};
                #pragma unroll
                for (int kt = 0; kt < 13; ++kt) {
                    bf16x8 h = *(const bf16x8*)(&bufC[aoff + kt * 32]);
                    a0 = __builtin_amdgcn_mfma_f32_16x16x32_bf16(breg[0][kt], h, a0, 0, 0, 0);
                    a1 = __builtin_amdgcn_mfma_f32_16x16x32_bf16(breg[1][kt], h, a1, 0, 0, 0);
                }

                // ---- in-register LSTM epilogue ----
                float zi = a0[0], zf = a0[1], zc = a0[2], zo = a0[3];
                if (l > 0) {
                    unsigned lo = (unsigned)zuA, hi = (unsigned)(zuA >> 32);
                    zi += bf_lo(lo); zf += bf_hi(lo); zc += bf_lo(hi); zo += bf_hi(hi);
                }
                float iv = sigm_(zi + piA * cA[gi]);
                float fv = sigm_(zf + pfA * cA[gi]);
                float cn = fv * cA[gi] + iv * tanh_(zc);
                float ov = sigm_(zo + poA * cn);
                float h0 = ov * tanh_(cn);
                cA[gi] = cn;
                zi = a1[0]; zf = a1[1]; zc = a1[2]; zo = a1[3];
                if (l > 0) {
                    unsigned lo = (unsigned)zuB, hi = (unsigned)(zuB >> 32);
                    zi += bf_lo(lo); zf += bf_hi(lo); zc += bf_lo(hi); zo += bf_hi(hi);
                }
                iv = sigm_(zi + piB * cB[gi]);
                fv = sigm_(zf + pfB * cB[gi]);
                cn = fv * cB[gi] + iv * tanh_(zc);
                ov = sigm_(zo + poB * cn);
                float h1 = ov * tanh_(cn);
                cB[gi] = cn;

                unsigned hu0 = f2bf(h0), hu1 = f2bf(h1);
                bufN[b * AS + ugA] = (unsigned short)hu0;    // own h -> next buffer
                bufN[b * AS + ugB] = (unsigned short)hu1;

                // hx[slot][u][b]: 64 consecutive dwords per wave store
                unsigned* hxs = hxG[gi] + (size_t)(t & 3) * 6400 + b;
                st_a(hxs + ugA * 16, ((unsigned)t << 16) | hu0);
                st_a(hxs + ugB * 16, ((unsigned)t << 16) | hu1);

                unsigned r0 = (unsigned)__shfl_xor((int)hu0, 16);   // partner q^1
                unsigned r1 = (unsigned)__shfl_xor((int)hu1, 16);
                if (l < 2) {
                    if (!(q & 1)) {   // hring[slot][u2][b]: 32 consecutive dwords/wave
                        unsigned* rg = ringG[gi] + (size_t)(t & 15) * 3200 + b;
                        st_a(rg + u2A * 16, hu0 | (r0 << 16));
                        st_a(rg + (u2A + 2) * 16, hu1 | (r1 << 16));
                    }
                } else {
                    if (t == TSTEPS - 1 && !(q & 1)) {   // final step: direct (one-time)
                        unsigned* hg = h2 + (size_t)t * 12800 + (size_t)(g * GB + b) * 200;
                        hg[u2A] = hu0 | (r0 << 16);
                        hg[u2A + 2] = hu1 | (r1 << 16);
                    }
                    if (s == 0 && t > 0) {   // coalesced dump of h(t-1) from staged A
                        for (int i = tid; i < 3200; i += 640) {
                            int bb2 = i / 200, u2 = i - bb2 * 200;
                            unsigned v2 = *(const unsigned*)&bufC[bb2 * AS + 2 * u2];
                            h2[(size_t)(t - 1) * 12800 + (size_t)(g * GB + bb2) * 200 + u2] = v2;
                        }
                    }
                }
            }
        }
        __syncthreads();
        if (tid < 2) st_a(FHownG[tid], (unsigned)TSTEPS);
    } else {
        // ---------------- preGEMM block (2 steps x 2 groups per iter) ----------------
        const int p = bid - 30;
        const int lz = p / 10;               // feeds layer lz+1
        const int gp = (p % 10) / 5;
        const int sp = p % 5;
        bf16x8 breg[2][13];
        #pragma unroll
        for (int n = 0; n < 2; ++n) {
            const unsigned short* bpp = Bpre + (size_t)lz * 1600 * KP
                + (size_t)(sp * CB + w * 32 + n * 16 + b) * KP + (q << 3);
            #pragma unroll
            for (int kt = 0; kt < 13; ++kt) breg[n][kt] = *(const bf16x8*)(bpp + kt * 32);
        }
        const unsigned* ringG[2]; unsigned* zinG[2];
        const unsigned* FHupG[2]; const unsigned* FHdnG[2]; unsigned* FZownG[2];
        #pragma unroll
        for (int gi = 0; gi < 2; ++gi) {
            int g = gp * 2 + gi;
            ringG[gi] = hring + (size_t)(lz * NG + g) * RD * 3200;
            zinG[gi] = zin + (size_t)(lz * NG + g) * RD * 12800;
            FHupG[gi] = seqb + ((lz * NG + g) * NSL) * 16;
            FHdnG[gi] = seqb + (((lz + 1) * NG + g) * NSL) * 16;
            FZownG[gi] = seqb + (60 + (lz * NG + g) * NSL + sp) * 16;
        }
        const int uA = sp * UB + w * 8 + q;
        const int uB = uA + 4;
        __syncthreads();

        for (int c = 0; c < TSTEPS; c += 2) {
            #pragma unroll
            for (int gi = 0; gi < 2; ++gi) {
                const int g = gp * 2 + gi;
                unsigned short* Ap = A + gi * (32 * AS);
                {   // ballot poll: h availability + zin-ring backpressure
                    const unsigned* fp = nullptr; unsigned need = 0;
                    if (tid < NSL) { fp = FHupG[gi] + tid * 16; need = (unsigned)(c + 2); }
                    else if (tid < 2 * NSL) { fp = FHdnG[gi] + (tid - NSL) * 16; need = (unsigned)(c > 14 ? c - 14 : 0); }
                    bool ok = (fp == nullptr) || (ld_a(fp) >= need);
                    while (!__all(ok)) { if (!ok) ok = ld_a(fp) >= need; }
                }
                __syncthreads();                       // B1 (prev chunk's zin stores drained)
                if (tid == 0 && c > 0) st_a(FZownG[gi], (unsigned)c);

                for (int i = tid; i < 6400; i += 640) {   // stage h(c),h(c+1): coalesced
                    int tc = (i >= 3200) ? 1 : 0;         // (round-6 bug was here)
                    int j2 = i - tc * 3200;
                    int u2 = j2 >> 4, bb2 = j2 & 15;
                    unsigned v = ld_a(ringG[gi] + (size_t)((c + tc) & 15) * 3200 + u2 * 16 + bb2);
                    *(unsigned*)&Ap[(tc * 16 + bb2) * AS + 2 * u2] = v;
                }
                if (tid < 32) {
                    int tc = tid >> 4, r = tid & 15;
                    *(uint2*)(&Ap[(tc * 16 + r) * AS + 400]) =
                        *(const uint2*)(xpack + ((size_t)(c + tc) * 64 + g * 16 + r) * 4);
                }
                __syncthreads();                       // B2

                floatx4 a00 = {0,0,0,0}, a01 = {0,0,0,0}, a10 = {0,0,0,0}, a11 = {0,0,0,0};
                #pragma unroll
                for (int kt = 0; kt < 13; ++kt) {
                    bf16x8 x0 = *(const bf16x8*)(&Ap[aoff + kt * 32]);
                    bf16x8 x1 = *(const bf16x8*)(&Ap[aoff + 16 * AS + kt * 32]);
                    a00 = __builtin_amdgcn_mfma_f32_16x16x32_bf16(breg[0][kt], x0, a00, 0, 0, 0);
                    a01 = __builtin_amdgcn_mfma_f32_16x16x32_bf16(breg[1][kt], x0, a01, 0, 0, 0);
                    a10 = __builtin_amdgcn_mfma_f32_16x16x32_bf16(breg[0][kt], x1, a10, 0, 0, 0);
                    a11 = __builtin_amdgcn_mfma_f32_16x16x32_bf16(breg[1][kt], x1, a11, 0, 0, 0);
                }
                {   // zin[slot][u][b] u64: contiguous 128-dword span per wave
                    unsigned* z0 = zinG[gi] + (size_t)(c & 15) * 12800;
                    unsigned* z1 = zinG[gi] + (size_t)((c + 1) & 15) * 12800;
                    int iA = uA * 32 + 2 * b, iB = uB * 32 + 2 * b;
                    st_a(z0 + iA,     (unsigned)f2bf(a00[0]) | ((unsigned)f2bf(a00[1]) << 16));
                    st_a(z0 + iA + 1, (unsigned)f2bf(a00[2]) | ((unsigned)f2bf(a00[3]) << 16));
                    st_a(z0 + iB,     (unsigned)f2bf(a01[0]) | ((unsigned)f2bf(a01[1]) << 16));
                    st_a(z0 + iB + 1, (unsigned)f2bf(a01[2]) | ((unsigned)f2bf(a01[3]) << 16));
                    st_a(z1 + iA,     (unsigned)f2bf(a10[0]) | ((unsigned)f2bf(a10[1]) << 16));
                    st_a(z1 + iA + 1, (unsigned)f2bf(a10[2]) | ((unsigned)f2bf(a10[3]) << 16));
                    st_a(z1 + iB,     (unsigned)f2bf(a11[0]) | ((unsigned)f2bf(a11[1]) << 16));
                    st_a(z1 + iB + 1, (unsigned)f2bf(a11[2]) | ((unsigned)f2bf(a11[3]) << 16));
                }
            }
        }
        __syncthreads();
        if (tid < 2) st_a(FZownG[tid], (unsigned)TSTEPS);
    }
}

// ---- MDN head ------------------------------------------------------------
__global__ __launch_bounds__(256)
void mdn_kernel(const unsigned short* __restrict__ h2,
                const unsigned short* __restrict__ Bm,
                float* __restrict__ out) {
    const int blk = blockIdx.x;
    const int bb = blk / 25;
    const int t0 = (blk - bb * 25) * 32;
    const int tid = threadIdx.x;
    const int lane = tid & 63;
    const int w = tid >> 6;
    const int m = w & 1, nh = w >> 1;

    __shared__ unsigned short A[32 * 424];
    __shared__ float Z[32 * 132];
    __shared__ float rmax[32], rinv[32];

    for (int i = tid; i < 32 * 424; i += 256) A[i] = 0;
    __syncthreads();
    for (int c = tid; c < 32 * 50; c += 256) {
        int r = c / 50, j = c - r * 50;
        *(bf16x8*)(&A[r * 424 + j * 8]) = *(const bf16x8*)(h2 + (size_t)(t0 + r) * 25600 + bb * 400 + j * 8);
    }
    if (tid < 32) A[tid * 424 + 400] = 0x3F80u;
    __syncthreads();

    floatx4 acc[4] = {{0,0,0,0},{0,0,0,0},{0,0,0,0},{0,0,0,0}};
    const int aoff = (m * 16 + (lane & 15)) * 424 + ((lane >> 4) << 3);
    #pragma unroll
    for (int kt = 0; kt < 13; ++kt) {
        bf16x8 a = *(const bf16x8*)(&A[aoff + kt * 32]);
        #pragma unroll
        for (int n = 0; n < 4; ++n) {
            const unsigned short* bp = Bm + (size_t)((nh * 4 + n) * 16 + (lane & 15)) * KP
                                          + ((lane >> 4) << 3) + kt * 32;
            acc[n] = __builtin_amdgcn_mfma_f32_16x16x32_bf16(a, *(const bf16x8*)bp, acc[n], 0, 0, 0);
        }
    }
    #pragma unroll
    for (int n = 0; n < 4; ++n) {
        int zc = (nh * 4 + n) * 16 + (lane & 15);
        int zrow = m * 16 + ((lane >> 4) << 2);
        #pragma unroll
        for (int ri = 0; ri < 4; ++ri)
            Z[(zrow + ri) * 132 + zc] = acc[n][ri];
    }
    __syncthreads();
    if (tid < 32) {
        float mx = -1e30f;
        for (int j = 0; j < 20; ++j) mx = fmaxf(mx, Z[tid * 132 + j]);
        float sm = 0.f;
        for (int j = 0; j < 20; ++j) sm += __expf(Z[tid * 132 + j] - mx);
        rmax[tid] = mx;
        rinv[tid] = 1.f / sm;
    }
    __syncthreads();
    for (int idx = tid; idx < 32 * 121; idx += 256) {
        int r = idx / 121, jo = idx - r * 121;
        float v = Z[r * 132 + jo];
        float o;
        if (jo < 20) o = __expf(v - rmax[r]) * rinv[r];
        else if (jo < 60) o = v;
        else if (jo < 100) o = __expf(v);
        else if (jo < 120) o = tanh_(v);
        else o = sigm_(v);
        out[(size_t)(bb * TSTEPS + t0 + r) * 121 + jo] = o;
    }
}

extern "C" void kernel_launch(void* const* d_in, const int* in_sizes, int n_in,
                              void* d_out, int out_size, void* d_ws, size_t ws_size,
                              hipStream_t stream) {
    const float* x = (const float*)d_in[0];
    const float* Wx[3] = {(const float*)d_in[1], (const float*)d_in[7], (const float*)d_in[13]};
    const float* Wh[3] = {(const float*)d_in[2], (const float*)d_in[8], (const float*)d_in[14]};
    const float* bb[3] = {(const float*)d_in[3], (const float*)d_in[9], (const float*)d_in[15]};
    Peeps pp;
    for (int l = 0; l < 3; ++l) {
        pp.pi[l] = (const float*)d_in[4 + 6 * l];
        pp.pf[l] = (const float*)d_in[5 + 6 * l];
        pp.po[l] = (const float*)d_in[6 + 6 * l];
    }
    const float* Wm = (const float*)d_in[19];
    const float* bm = (const float*)d_in[20];
    float* out = (float*)d_out;

    char* base = (char*)d_ws;
    size_t off = 0;
    auto alloc = [&](size_t bytes) -> void* {
        void* r = base + off;
        off = (off + bytes + 255) & ~(size_t)255;
        return r;
    };
    unsigned* seqb        = (unsigned*)alloc(1600 * sizeof(unsigned));              // 6.4 KB
    unsigned* hx          = (unsigned*)alloc((size_t)3 * NG * HXD * 6400 * 4);      // 1.23 MB
    unsigned* hring       = (unsigned*)alloc((size_t)3 * NG * RD * 3200 * 4);       // 2.46 MB
    unsigned* zin         = (unsigned*)alloc((size_t)2 * NG * RD * 12800 * 4);      // 6.55 MB
    unsigned short* Bp    = (unsigned short*)alloc((size_t)3 * 1600 * KP * 2);      // 4.0 MB
    unsigned short* Bpre  = (unsigned short*)alloc((size_t)2 * 1600 * KP * 2);      // 2.7 MB
    unsigned short* Bm    = (unsigned short*)alloc((size_t)128 * KP * 2);
    unsigned short* xpk   = (unsigned short*)alloc((size_t)TSTEPS * 64 * 4 * 2);
    unsigned short* h2    = (unsigned short*)alloc((size_t)TSTEPS * 64 * 400 * 2);  // 41 MB

    hipMemsetAsync(seqb, 0, 1600 * sizeof(unsigned), stream);
    hipMemsetAsync(hx, 0xAA, (size_t)3 * NG * HXD * 6400 * 4, stream);  // tags can't alias

    for (int l = 0; l < 3; ++l)
        pack_rec<<<2600, 256, 0, stream>>>(Wx[l], Wh[l], bb[l], Bp + (size_t)l * 1600 * KP, l == 0);
    pack_pre<<<2600, 256, 0, stream>>>(Wx[1], bb[1], Bpre);
    pack_pre<<<2600, 256, 0, stream>>>(Wx[2], bb[2], Bpre + (size_t)1600 * KP);
    pack_x<<<200, 256, 0, stream>>>(x, xpk);
    pack_mdn<<<208, 256, 0, stream>>>(Wm, bm, Bm);

    fused_scan<<<50, 640, 0, stream>>>(Bp, Bpre, xpk, hx, hring, zin, seqb,
                                       (unsigned*)h2, pp);

    mdn_kernel<<<1600, 256, 0, stream>>>(h2, Bm, out);
}

// Round 8
// 5104.657 us; speedup vs baseline: 2.1728x; 2.1728x over previous
//
#include <hip/hip_runtime.h>

// DeepHandwritingPredictionModel: 3-layer peephole LSTM (B=64,T=800,U=400) + MDN(M=20)
// Round 8: round-4 topology (60 rec + 40 pre blocks, 1 group each, proven 3.0ms
// protocol) + in-register LSTM epilogue (operand-swapped MFMA, 1 barrier/step)
// + unit-major coalesced exchange layouts. Group-pair multiplexing (r7) reverted.

#define TSTEPS 800
#define NG 4            // batch groups
#define GB 16           // batches per group
#define NSL 5           // slices / splits per (layer,group)
#define UB 80           // units per slice
#define CB 320          // cols per slice (4 gates * UB)
#define KP 416          // padded K (400 h | 3 x | 1 one | pad)
#define RD 16           // hring / zin ring depth
#define HXD 4           // tagged hx ring depth
#define AS 424          // A LDS stride (bf16)

typedef __attribute__((ext_vector_type(8))) __bf16 bf16x8;
typedef __attribute__((ext_vector_type(4))) float floatx4;

struct Peeps { const float* pi[3]; const float* pf[3]; const float* po[3]; };

__device__ __forceinline__ unsigned short f2bf(float f) {
    unsigned int u = __float_as_uint(f);
    return (unsigned short)((u + 0x7FFFu + ((u >> 16) & 1u)) >> 16);
}
__device__ __forceinline__ float bf_lo(unsigned u) { return __uint_as_float(u << 16); }
__device__ __forceinline__ float bf_hi(unsigned u) { return __uint_as_float(u & 0xFFFF0000u); }
__device__ __forceinline__ float sigm_(float v) { return 1.f / (1.f + __expf(-v)); }
__device__ __forceinline__ float tanh_(float v) { float e = __expf(2.f * v); return 1.f - 2.f / (e + 1.f); }
__device__ __forceinline__ unsigned ld_a(const unsigned* p) {
    return __hip_atomic_load(p, __ATOMIC_RELAXED, __HIP_MEMORY_SCOPE_AGENT);
}
__device__ __forceinline__ unsigned long long ld_a64(const unsigned long long* p) {
    return __hip_atomic_load(p, __ATOMIC_RELAXED, __HIP_MEMORY_SCOPE_AGENT);
}
__device__ __forceinline__ void st_a(unsigned* p, unsigned v) {
    __hip_atomic_store(p, v, __ATOMIC_RELAXED, __HIP_MEMORY_SCOPE_AGENT);
}

// ---- weight packing ------------------------------------------------------
__global__ void pack_rec(const float* __restrict__ Wx, const float* __restrict__ Wh,
                         const float* __restrict__ bias, unsigned short* __restrict__ dst,
                         int is_l0) {
    int idx = blockIdx.x * 256 + threadIdx.x;
    if (idx >= 1600 * KP) return;
    int col = idx / KP, k = idx - col * KP;
    int co = (col & 3) * 400 + (col >> 2);
    float v = 0.f;
    if (k < 400) v = Wh[k * 1600 + co];
    else if (is_l0) {
        if (k < 403) v = Wx[(k - 400) * 1600 + co];
        else if (k == 403) v = bias[co];
    }
    dst[idx] = f2bf(v);
}
__global__ void pack_pre(const float* __restrict__ Wx, const float* __restrict__ bias,
                         unsigned short* __restrict__ dst) {
    int idx = blockIdx.x * 256 + threadIdx.x;
    if (idx >= 1600 * KP) return;
    int col = idx / KP, k = idx - col * KP;
    int co = (col & 3) * 400 + (col >> 2);
    float v = 0.f;
    if (k < 400) v = Wx[(3 + k) * 1600 + co];
    else if (k < 403) v = Wx[(k - 400) * 1600 + co];
    else if (k == 403) v = bias[co];
    dst[idx] = f2bf(v);
}
__global__ void pack_x(const float* __restrict__ x, unsigned short* __restrict__ xp) {
    int idx = blockIdx.x * 256 + threadIdx.x;   // idx = t*64 + b
    if (idx >= TSTEPS * 64) return;
    int t = idx / 64, b = idx - t * 64;
    unsigned short o[4];
    for (int d = 0; d < 3; ++d) o[d] = f2bf(x[(b * TSTEPS + t) * 3 + d]);
    o[3] = 0x3F80u;
    *(uint2*)(xp + (size_t)idx * 4) = *(uint2*)o;
}
__global__ void pack_mdn(const float* __restrict__ Wm, const float* __restrict__ bm,
                         unsigned short* __restrict__ dst) {
    int idx = blockIdx.x * 256 + threadIdx.x;
    if (idx >= 128 * KP) return;
    int col = idx / KP, k = idx - col * KP;
    float v = 0.f;
    if (col < 121) {
        if (k < 400) v = Wm[k * 121 + col];
        else if (k == 400) v = bm[col];
    }
    dst[idx] = f2bf(v);
}

// ---- fused pipeline ------------------------------------------------------
// grid 100 x 640: bid<60 rec (l=bid/20, g=(bid%20)/5, s=bid%5); else pre.
// hx   : [3][NG][HXD][400][16] u32 tagged (t<<16|bf16), slot t&3
// hring: [3][NG][RD][200][16] u32 packed 2xbf16, slot t&15 (for pre)
// zin  : [2][NG][RD][400][16] u64 (4 gates as 4xbf16), slot t&15
// seqb : FH[(l*NG+g)*NSL+s]*16 ; FZ at +60*16: [(lz*NG+g)*NSL+sp]*16
__global__ __launch_bounds__(640)
void fused_scan(const unsigned short* __restrict__ Bp,
                const unsigned short* __restrict__ Bpre,
                const unsigned short* __restrict__ xpack,
                unsigned* __restrict__ hx,
                unsigned* __restrict__ hring,
                unsigned* __restrict__ zin,
                unsigned* __restrict__ seqb,
                unsigned* __restrict__ h2,      // [T][64][200] dwords (2xbf16)
                Peeps pp) {
    const int tid = threadIdx.x;
    const int lane = tid & 63;
    const int w = tid >> 6;
    const int bid = blockIdx.x;

    __shared__ unsigned short A[2 * 16 * AS];   // rec: 2 bufs of 16 rows; pre: [32][AS]

    for (int i = tid; i < 2 * 16 * AS; i += 640) A[i] = 0;

    const int bs = tid & 15;          // staging batch
    const int ms = tid >> 4;          // staging unit-index 0..39
    const int aoff = (lane & 15) * AS + ((lane >> 4) << 3);
    const int b = lane & 15;          // epilogue batch
    const int q = lane >> 4;          // epilogue unit-within-8 (0..3)

    if (bid < 60) {
        // ---------------- recurrence block ----------------
        const int l = bid / 20;
        const int g = (bid % 20) / 5;
        const int s = bid % 5;
        bf16x8 breg[2][13];
        #pragma unroll
        for (int n = 0; n < 2; ++n) {
            const unsigned short* bpp = Bp + (size_t)l * 1600 * KP
                + (size_t)(s * CB + w * 32 + n * 16 + b) * KP + (q << 3);
            #pragma unroll
            for (int kt = 0; kt < 13; ++kt) breg[n][kt] = *(const bf16x8*)(bpp + kt * 32);
        }
        // poll mapping: 8 peer-units per thread (u-major coalesced)
        int offs[8], us[8];
        #pragma unroll
        for (int j = 0; j < 8; ++j) {
            int m = ms + 40 * j;
            int u = m + (m >= s * UB ? UB : 0);
            us[j] = u; offs[j] = u * 16 + bs;
        }
        unsigned* hxL = hx + (size_t)(l * NG + g) * HXD * 6400;
        unsigned* ringL = hring + (size_t)(l * NG + g) * RD * 3200;
        const unsigned long long* zinL =
            (const unsigned long long*)(zin + (size_t)((l - 1) * NG + g) * RD * 12800);
        unsigned* FHown = seqb + ((l * NG + g) * NSL + s) * 16;
        const unsigned* FZup = seqb + (60 + ((l - 1) * NG + g) * NSL) * 16;
        const unsigned* FZdn = seqb + (60 + (l * NG + g) * NSL) * 16;

        const int ugA = s * UB + w * 8 + q;      // epilogue unit A
        const int ugB = ugA + 4;                 // epilogue unit B
        const int u2A = s * 40 + w * 4 + (q >> 1);
        const float piA = pp.pi[l][ugA], pfA = pp.pf[l][ugA], poA = pp.po[l][ugA];
        const float piB = pp.pi[l][ugB], pfB = pp.pf[l][ugB], poB = pp.po[l][ugB];
        float cA = 0.f, cB = 0.f;
        __syncthreads();

        for (int t = 0; t < TSTEPS; ++t) {
            unsigned short* bufC = A + (t & 1) * (16 * AS);
            unsigned short* bufN = A + ((t + 1) & 1) * (16 * AS);
            // ---- poll peers' tagged h(t-1) + amortized flag gates ----
            {
                const unsigned want = (unsigned)(t - 1) << 16;
                const unsigned* hb = hxL + (size_t)((t + 3) & 3) * 6400;
                const unsigned* fp = nullptr; unsigned fneed = 0;
                if (l > 0 && (t & 3) == 0 && tid < NSL) { fp = FZup + tid * 16; fneed = (unsigned)(t + 4); }
                else if (l < 2 && (t & 7) == 0 && tid >= NSL && tid < 2 * NSL) {
                    fp = FZdn + (tid - NSL) * 16; fneed = (unsigned)(t > 8 ? t - 8 : 0);
                }
                unsigned v[8];
                for (;;) {
                    bool ok = true;
                    if (t > 0) {
                        #pragma unroll
                        for (int j = 0; j < 8; ++j) {
                            v[j] = ld_a(hb + offs[j]);
                            ok &= ((v[j] & 0xFFFF0000u) == want);
                        }
                    }
                    if (fp) ok &= (ld_a(fp) >= fneed);
                    if (__all(ok)) break;
                }
                if (t > 0) {
                    #pragma unroll
                    for (int j = 0; j < 8; ++j)
                        bufC[bs * AS + us[j]] = (unsigned short)v[j];
                }
            }
            if (l == 0 && tid < 16)
                *(uint2*)(&bufC[tid * AS + 400]) = *(const uint2*)(xpack + ((size_t)t * 64 + g * 16 + tid) * 4);
            __syncthreads();                        // B1 (only barrier per step)
            if (tid == 0) st_a(FHown, (unsigned)t); // h(0..t-1) hring-visible

            unsigned long long zuA = 0, zuB = 0;
            if (l > 0) {                            // zin(t): latency hidden under MFMA
                const unsigned long long* zp = zinL + (size_t)(t & 15) * 6400 + b;
                zuA = ld_a64(zp + ugA * 16);
                zuB = ld_a64(zp + ugB * 16);
            }

            floatx4 a0 = {0, 0, 0, 0}, a1 = {0, 0, 0, 0};
            #pragma unroll
            for (int kt = 0; kt < 13; ++kt) {
                bf16x8 h = *(const bf16x8*)(&bufC[aoff + kt * 32]);
                a0 = __builtin_amdgcn_mfma_f32_16x16x32_bf16(breg[0][kt], h, a0, 0, 0, 0);
                a1 = __builtin_amdgcn_mfma_f32_16x16x32_bf16(breg[1][kt], h, a1, 0, 0, 0);
            }

            // ---- in-register LSTM epilogue: lane owns (batch b, units ugA,ugB) ----
            float zi = a0[0], zf = a0[1], zc = a0[2], zo = a0[3];
            if (l > 0) {
                unsigned lo = (unsigned)zuA, hi = (unsigned)(zuA >> 32);
                zi += bf_lo(lo); zf += bf_hi(lo); zc += bf_lo(hi); zo += bf_hi(hi);
            }
            float iv = sigm_(zi + piA * cA);
            float fv = sigm_(zf + pfA * cA);
            float cn = fv * cA + iv * tanh_(zc);
            float ov = sigm_(zo + poA * cn);
            float h0 = ov * tanh_(cn);
            cA = cn;
            zi = a1[0]; zf = a1[1]; zc = a1[2]; zo = a1[3];
            if (l > 0) {
                unsigned lo = (unsigned)zuB, hi = (unsigned)(zuB >> 32);
                zi += bf_lo(lo); zf += bf_hi(lo); zc += bf_lo(hi); zo += bf_hi(hi);
            }
            iv = sigm_(zi + piB * cB);
            fv = sigm_(zf + pfB * cB);
            cn = fv * cB + iv * tanh_(zc);
            ov = sigm_(zo + poB * cn);
            float h1 = ov * tanh_(cn);
            cB = cn;

            unsigned hu0 = f2bf(h0), hu1 = f2bf(h1);
            bufN[b * AS + ugA] = (unsigned short)hu0;    // own h(t) -> next buffer
            bufN[b * AS + ugB] = (unsigned short)hu1;

            // hx[slot][u][b]: 64 consecutive dwords per wave store
            unsigned* hxs = hxL + (size_t)(t & 3) * 6400 + b;
            st_a(hxs + ugA * 16, ((unsigned)t << 16) | hu0);
            st_a(hxs + ugB * 16, ((unsigned)t << 16) | hu1);

            if (l < 2) {
                unsigned r0 = (unsigned)__shfl_xor((int)hu0, 16);   // partner q^1
                unsigned r1 = (unsigned)__shfl_xor((int)hu1, 16);
                if (!(q & 1)) {   // hring[slot][u2][b]: 32 consecutive dwords/wave
                    unsigned* rg = ringL + (size_t)(t & 15) * 3200 + b;
                    st_a(rg + u2A * 16, hu0 | (r0 << 16));
                    st_a(rg + (u2A + 2) * 16, hu1 | (r1 << 16));
                }
            } else {
                if (t > 0) {   // coalesced 1-dword/thread dump of h(t-1), split by slice
                    int i = s * 640 + tid;
                    int bb2 = i / 200, u2 = i - bb2 * 200;
                    unsigned v2 = *(const unsigned*)&bufC[bb2 * AS + 2 * u2];
                    h2[(size_t)(t - 1) * 12800 + (size_t)(g * GB + bb2) * 200 + u2] = v2;
                }
                if (t == TSTEPS - 1) {   // final step: direct store (one-time)
                    unsigned r0 = (unsigned)__shfl_xor((int)hu0, 16);
                    unsigned r1 = (unsigned)__shfl_xor((int)hu1, 16);
                    if (!(q & 1)) {
                        unsigned* hg = h2 + (size_t)t * 12800 + (size_t)(g * GB + b) * 200;
                        hg[u2A] = hu0 | (r0 << 16);
                        hg[u2A + 2] = hu1 | (r1 << 16);
                    }
                }
            }
        }
        __syncthreads();
        if (tid == 0) st_a(FHown, (unsigned)TSTEPS);
    } else {
        // ---------------- preGEMM block (TCH=2 steps per chunk) ----------------
        const int p = bid - 60;
        const int lz = p / 20;               // feeds layer lz+1
        const int g = (p % 20) / 5;
        const int sp = p % 5;
        bf16x8 breg[2][13];
        #pragma unroll
        for (int n = 0; n < 2; ++n) {
            const unsigned short* bpp = Bpre + (size_t)lz * 1600 * KP
                + (size_t)(sp * CB + w * 32 + n * 16 + b) * KP + (q << 3);
            #pragma unroll
            for (int kt = 0; kt < 13; ++kt) breg[n][kt] = *(const bf16x8*)(bpp + kt * 32);
        }
        const unsigned* ringS = hring + (size_t)(lz * NG + g) * RD * 3200;
        unsigned* zinD = zin + (size_t)(lz * NG + g) * RD * 12800;
        const unsigned* FHup = seqb + ((lz * NG + g) * NSL) * 16;
        const unsigned* FHdn = seqb + (((lz + 1) * NG + g) * NSL) * 16;
        unsigned* FZown = seqb + (60 + (lz * NG + g) * NSL + sp) * 16;
        const int uA = sp * UB + w * 8 + q;
        const int uB = uA + 4;
        __syncthreads();

        for (int c = 0; c < TSTEPS; c += 2) {
            {   // ballot poll: h availability + zin-ring backpressure
                const unsigned* fp = nullptr; unsigned need = 0;
                if (tid < NSL) { fp = FHup + tid * 16; need = (unsigned)(c + 2); }
                else if (tid < 2 * NSL) { fp = FHdn + (tid - NSL) * 16; need = (unsigned)(c > 14 ? c - 14 : 0); }
                bool ok = (fp == nullptr) || (ld_a(fp) >= need);
                while (!__all(ok)) { if (!ok) ok = ld_a(fp) >= need; }
            }
            __syncthreads();                       // B1 (prev chunk's zin stores drained)
            if (tid == 0 && c > 0) st_a(FZown, (unsigned)c);   // zin(0..c-1) visible

            for (int i = tid; i < 6400; i += 640) {   // stage h(c),h(c+1): coalesced
                int tc = (i >= 3200) ? 1 : 0;
                int j2 = i - tc * 3200;
                int u2 = j2 >> 4, bb2 = j2 & 15;
                unsigned v = ld_a(ringS + (size_t)((c + tc) & 15) * 3200 + u2 * 16 + bb2);
                *(unsigned*)&A[(tc * 16 + bb2) * AS + 2 * u2] = v;
            }
            if (tid < 32) {
                int tc = tid >> 4, r = tid & 15;
                *(uint2*)(&A[(tc * 16 + r) * AS + 400]) =
                    *(const uint2*)(xpack + ((size_t)(c + tc) * 64 + g * 16 + r) * 4);
            }
            __syncthreads();                       // B2

            floatx4 a00 = {0,0,0,0}, a01 = {0,0,0,0}, a10 = {0,0,0,0}, a11 = {0,0,0,0};
            #pragma unroll
            for (int kt = 0; kt < 13; ++kt) {
                bf16x8 x0 = *(const bf16x8*)(&A[aoff + kt * 32]);
                bf16x8 x1 = *(const bf16x8*)(&A[aoff + 16 * AS + kt * 32]);
                a00 = __builtin_amdgcn_mfma_f32_16x16x32_bf16(breg[0][kt], x0, a00, 0, 0, 0);
                a01 = __builtin_amdgcn_mfma_f32_16x16x32_bf16(breg[1][kt], x0, a01, 0, 0, 0);
                a10 = __builtin_amdgcn_mfma_f32_16x16x32_bf16(breg[0][kt], x1, a10, 0, 0, 0);
                a11 = __builtin_amdgcn_mfma_f32_16x16x32_bf16(breg[1][kt], x1, a11, 0, 0, 0);
            }
            {   // zin[slot][u][b] u64: contiguous 32-dword span per (w,q,n)
                unsigned* z0 = zinD + (size_t)(c & 15) * 12800;
                unsigned* z1 = zinD + (size_t)((c + 1) & 15) * 12800;
                int iA = uA * 32 + 2 * b, iB = uB * 32 + 2 * b;
                st_a(z0 + iA,     (unsigned)f2bf(a00[0]) | ((unsigned)f2bf(a00[1]) << 16));
                st_a(z0 + iA + 1, (unsigned)f2bf(a00[2]) | ((unsigned)f2bf(a00[3]) << 16));
                st_a(z0 + iB,     (unsigned)f2bf(a01[0]) | ((unsigned)f2bf(a01[1]) << 16));
                st_a(z0 + iB + 1, (unsigned)f2bf(a01[2]) | ((unsigned)f2bf(a01[3]) << 16));
                st_a(z1 + iA,     (unsigned)f2bf(a10[0]) | ((unsigned)f2bf(a10[1]) << 16));
                st_a(z1 + iA + 1, (unsigned)f2bf(a10[2]) | ((unsigned)f2bf(a10[3]) << 16));
                st_a(z1 + iB,     (unsigned)f2bf(a11[0]) | ((unsigned)f2bf(a11[1]) << 16));
                st_a(z1 + iB + 1, (unsigned)f2bf(a11[2]) | ((unsigned)f2bf(a11[3]) << 16));
            }
        }
        __syncthreads();
        if (tid == 0) st_a(FZown, (unsigned)TSTEPS);
    }
}

// ---- MDN head ------------------------------------------------------------
__global__ __launch_bounds__(256)
void mdn_kernel(const unsigned short* __restrict__ h2,
                const unsigned short* __restrict__ Bm,
                float* __restrict__ out) {
    const int blk = blockIdx.x;
    const int bb = blk / 25;
    const int t0 = (blk - bb * 25) * 32;
    const int tid = threadIdx.x;
    const int lane = tid & 63;
    const int w = tid >> 6;
    const int m = w & 1, nh = w >> 1;

    __shared__ unsigned short A[32 * 424];
    __shared__ float Z[32 * 132];
    __shared__ float rmax[32], rinv[32];

    for (int i = tid; i < 32 * 424; i += 256) A[i] = 0;
    __syncthreads();
    for (int c = tid; c < 32 * 50; c += 256) {
        int r = c / 50, j = c - r * 50;
        *(bf16x8*)(&A[r * 424 + j * 8]) = *(const bf16x8*)(h2 + (size_t)(t0 + r) * 25600 + bb * 400 + j * 8);
    }
    if (tid < 32) A[tid * 424 + 400] = 0x3F80u;
    __syncthreads();

    floatx4 acc[4] = {{0,0,0,0},{0,0,0,0},{0,0,0,0},{0,0,0,0}};
    const int aoff = (m * 16 + (lane & 15)) * 424 + ((lane >> 4) << 3);
    #pragma unroll
    for (int kt = 0; kt < 13; ++kt) {
        bf16x8 a = *(const bf16x8*)(&A[aoff + kt * 32]);
        #pragma unroll
        for (int n = 0; n < 4; ++n) {
            const unsigned short* bp = Bm + (size_t)((nh * 4 + n) * 16 + (lane & 15)) * KP
                                          + ((lane >> 4) << 3) + kt * 32;
            acc[n] = __builtin_amdgcn_mfma_f32_16x16x32_bf16(a, *(const bf16x8*)bp, acc[n], 0, 0, 0);
        }
    }
    #pragma unroll
    for (int n = 0; n < 4; ++n) {
        int zc = (nh * 4 + n) * 16 + (lane & 15);
        int zrow = m * 16 + ((lane >> 4) << 2);
        #pragma unroll
        for (int ri = 0; ri < 4; ++ri)
            Z[(zrow + ri) * 132 + zc] = acc[n][ri];
    }
    __syncthreads();
    if (tid < 32) {
        float mx = -1e30f;
        for (int j = 0; j < 20; ++j) mx = fmaxf(mx, Z[tid * 132 + j]);
        float sm = 0.f;
        for (int j = 0; j < 20; ++j) sm += __expf(Z[tid * 132 + j] - mx);
        rmax[tid] = mx;
        rinv[tid] = 1.f / sm;
    }
    __syncthreads();
    for (int idx = tid; idx < 32 * 121; idx += 256) {
        int r = idx / 121, jo = idx - r * 121;
        float v = Z[r * 132 + jo];
        float o;
        if (jo < 20) o = __expf(v - rmax[r]) * rinv[r];
        else if (jo < 60) o = v;
        else if (jo < 100) o = __expf(v);
        else if (jo < 120) o = tanh_(v);
        else o = sigm_(v);
        out[(size_t)(bb * TSTEPS + t0 + r) * 121 + jo] = o;
    }
}

extern "C" void kernel_launch(void* const* d_in, const int* in_sizes, int n_in,
                              void* d_out, int out_size, void* d_ws, size_t ws_size,
                              hipStream_t stream) {
    const float* x = (const float*)d_in[0];
    const float* Wx[3] = {(const float*)d_in[1], (const float*)d_in[7], (const float*)d_in[13]};
    const float* Wh[3] = {(const float*)d_in[2], (const float*)d_in[8], (const float*)d_in[14]};
    const float* bb[3] = {(const float*)d_in[3], (const float*)d_in[9], (const float*)d_in[15]};
    Peeps pp;
    for (int l = 0; l < 3; ++l) {
        pp.pi[l] = (const float*)d_in[4 + 6 * l];
        pp.pf[l] = (const float*)d_in[5 + 6 * l];
        pp.po[l] = (const float*)d_in[6 + 6 * l];
    }
    const float* Wm = (const float*)d_in[19];
    const float* bm = (const float*)d_in[20];
    float* out = (float*)d_out;

    char* base = (char*)d_ws;
    size_t off = 0;
    auto alloc = [&](size_t bytes) -> void* {
        void* r = base + off;
        off = (off + bytes + 255) & ~(size_t)255;
        return r;
    };
    unsigned* seqb        = (unsigned*)alloc(1600 * sizeof(unsigned));              // 6.4 KB
    unsigned* hx          = (unsigned*)alloc((size_t)3 * NG * HXD * 6400 * 4);      // 1.23 MB
    unsigned* hring       = (unsigned*)alloc((size_t)3 * NG * RD * 3200 * 4);       // 2.46 MB
    unsigned* zin         = (unsigned*)alloc((size_t)2 * NG * RD * 12800 * 4);      // 6.55 MB
    unsigned short* Bp    = (unsigned short*)alloc((size_t)3 * 1600 * KP * 2);      // 4.0 MB
    unsigned short* Bpre  = (unsigned short*)alloc((size_t)2 * 1600 * KP * 2);      // 2.7 MB
    unsigned short* Bm    = (unsigned short*)alloc((size_t)128 * KP * 2);
    unsigned short* xpk   = (unsigned short*)alloc((size_t)TSTEPS * 64 * 4 * 2);
    unsigned short* h2    = (unsigned short*)alloc((size_t)TSTEPS * 64 * 400 * 2);  // 41 MB

    hipMemsetAsync(seqb, 0, 1600 * sizeof(unsigned), stream);
    hipMemsetAsync(hx, 0xAA, (size_t)3 * NG * HXD * 6400 * 4, stream);  // tags can't alias

    for (int l = 0; l < 3; ++l)
        pack_rec<<<2600, 256, 0, stream>>>(Wx[l], Wh[l], bb[l], Bp + (size_t)l * 1600 * KP, l == 0);
    pack_pre<<<2600, 256, 0, stream>>>(Wx[1], bb[1], Bpre);
    pack_pre<<<2600, 256, 0, stream>>>(Wx[2], bb[2], Bpre + (size_t)1600 * KP);
    pack_x<<<200, 256, 0, stream>>>(x, xpk);
    pack_mdn<<<208, 256, 0, stream>>>(Wm, bm, Bm);

    fused_scan<<<100, 640, 0, stream>>>(Bp, Bpre, xpk, hx, hring, zin, seqb,
                                        (unsigned*)h2, pp);

    mdn_kernel<<<1600, 256, 0, stream>>>(h2, Bm, out);
}

// Round 9
// 3267.016 us; speedup vs baseline: 3.3949x; 1.5625x over previous
//
#include <hip/hip_runtime.h>

// DeepHandwritingPredictionModel: 3-layer peephole LSTM (B=64,T=800,U=400) + MDN(M=20)
// Round 9 = Round 4 (best verified, 3.03ms) + XCD clustering ONLY.
//   Grid 200: block bid -> XCD bid%8 (HW round-robin). Odd XCDs exit; group
//   g = (bid&7)>>1 owns XCD 2g; idx = bid>>3 in [0,25): 0-14 rec(l=idx/5,s=idx%5),
//   15-24 pre(lz=(idx-15)/5,sp=idx%5). All of a group's exchange traffic (hx/hring/
//   zin/flags) becomes XCD-local L2 instead of LLC. Agent-scope atomics keep
//   correctness independent of the mapping; only latency depends on it.

#define TSTEPS 800
#define NG 4            // batch groups
#define GB 16           // batches per group
#define NSL 5           // slices / splits per (layer,group)
#define UB 80           // units per slice
#define CB 320          // cols per slice (4 gates * UB)
#define KP 416          // padded K (400 h | 3 x | 1 one | pad)
#define RD 16           // hring / zin ring depth
#define HXD 4           // tagged hx ring depth
#define AS 424          // A LDS stride (bf16)
#define ZS 332          // Z LDS stride (f32)

typedef __attribute__((ext_vector_type(8))) __bf16 bf16x8;
typedef __attribute__((ext_vector_type(4))) float floatx4;

struct Peeps { const float* pi[3]; const float* pf[3]; const float* po[3]; };

__device__ __forceinline__ unsigned short f2bf(float f) {
    unsigned int u = __float_as_uint(f);
    return (unsigned short)((u + 0x7FFFu + ((u >> 16) & 1u)) >> 16);
}
__device__ __forceinline__ float bf_lo(unsigned u) { return __uint_as_float(u << 16); }
__device__ __forceinline__ float bf_hi(unsigned u) { return __uint_as_float(u & 0xFFFF0000u); }
__device__ __forceinline__ float sigm_(float v) { return 1.f / (1.f + __expf(-v)); }
__device__ __forceinline__ float tanh_(float v) { float e = __expf(2.f * v); return 1.f - 2.f / (e + 1.f); }
__device__ __forceinline__ unsigned ld_a(const unsigned* p) {
    return __hip_atomic_load(p, __ATOMIC_RELAXED, __HIP_MEMORY_SCOPE_AGENT);
}
__device__ __forceinline__ void st_a(unsigned* p, unsigned v) {
    __hip_atomic_store(p, v, __ATOMIC_RELAXED, __HIP_MEMORY_SCOPE_AGENT);
}

// ---- weight packing ------------------------------------------------------
__global__ void pack_rec(const float* __restrict__ Wx, const float* __restrict__ Wh,
                         const float* __restrict__ bias, unsigned short* __restrict__ dst,
                         int is_l0) {
    int idx = blockIdx.x * 256 + threadIdx.x;
    if (idx >= 1600 * KP) return;
    int col = idx / KP, k = idx - col * KP;
    int co = (col & 3) * 400 + (col >> 2);
    float v = 0.f;
    if (k < 400) v = Wh[k * 1600 + co];
    else if (is_l0) {
        if (k < 403) v = Wx[(k - 400) * 1600 + co];
        else if (k == 403) v = bias[co];
    }
    dst[idx] = f2bf(v);
}
__global__ void pack_pre(const float* __restrict__ Wx, const float* __restrict__ bias,
                         unsigned short* __restrict__ dst) {
    int idx = blockIdx.x * 256 + threadIdx.x;
    if (idx >= 1600 * KP) return;
    int col = idx / KP, k = idx - col * KP;
    int co = (col & 3) * 400 + (col >> 2);
    float v = 0.f;
    if (k < 400) v = Wx[(3 + k) * 1600 + co];
    else if (k < 403) v = Wx[(k - 400) * 1600 + co];
    else if (k == 403) v = bias[co];
    dst[idx] = f2bf(v);
}
__global__ void pack_x(const float* __restrict__ x, unsigned short* __restrict__ xp) {
    int idx = blockIdx.x * 256 + threadIdx.x;   // idx = t*64 + b
    if (idx >= TSTEPS * 64) return;
    int t = idx / 64, b = idx - t * 64;
    unsigned short o[4];
    for (int d = 0; d < 3; ++d) o[d] = f2bf(x[(b * TSTEPS + t) * 3 + d]);
    o[3] = 0x3F80u;
    *(uint2*)(xp + (size_t)idx * 4) = *(uint2*)o;
}
__global__ void pack_mdn(const float* __restrict__ Wm, const float* __restrict__ bm,
                         unsigned short* __restrict__ dst) {
    int idx = blockIdx.x * 256 + threadIdx.x;
    if (idx >= 128 * KP) return;
    int col = idx / KP, k = idx - col * KP;
    float v = 0.f;
    if (col < 121) {
        if (k < 400) v = Wm[k * 121 + col];
        else if (k == 400) v = bm[col];
    }
    dst[idx] = f2bf(v);
}

// ---- fused pipeline ------------------------------------------------------
// grid 200 x 640; active iff (bid&7) even; g=(bid&7)>>1; idx=bid>>3 in [0,25).
// hx   : [3][NG][HXD][16][400] u32 tagged (t<<16|bf16), slot t&3
// hring: [3][NG][RD][16][200] u32 packed 2xbf16, slot t&15 (for pre)
// zin  : [2][NG][RD][16][800] u32 packed 2xbf16, slot t&15
// seqb : FH[(l*NG+g)*NSL+s]*16 ; FZ at +60*16: [(lz*NG+g)*NSL+sp]*16
__global__ __launch_bounds__(640)
void fused_scan(const unsigned short* __restrict__ Bp,
                const unsigned short* __restrict__ Bpre,
                const unsigned short* __restrict__ xpack,
                unsigned* __restrict__ hx,
                unsigned* __restrict__ hring,
                unsigned* __restrict__ zin,
                unsigned* __restrict__ seqb,
                unsigned* __restrict__ h2,      // [T][64][200] dwords (2xbf16)
                Peeps pp) {
    const int tid = threadIdx.x;
    const int lane = tid & 63;
    const int w = tid >> 6;
    const int bid = blockIdx.x;

    const int xcd = bid & 7;
    if (xcd & 1) return;              // odd-XCD blocks idle (locality layout)
    const int g = xcd >> 1;           // group g's whole pipeline on XCD 2g
    const int idx = bid >> 3;         // 0..24: role within the group

    __shared__ unsigned short A[32 * AS];
    __shared__ float Z[16 * ZS];

    for (int i = tid; i < 32 * AS; i += 640) A[i] = 0;

    const int er = tid / 40;          // batch row 0..15
    const int up = tid - er * 40;     // unit-pair 0..39
    const int aoff = (lane & 15) * AS + ((lane >> 4) << 3);
    const int zc0 = w * 32 + (lane & 15);
    const int zr = (lane >> 4) << 2;

    if (idx < 15) {
        // ---------------- recurrence block ----------------
        const int l = idx / 5;
        const int s = idx - l * 5;
        bf16x8 breg[2][13];
        #pragma unroll
        for (int n = 0; n < 2; ++n) {
            const unsigned short* bpp = Bp + (size_t)l * 1600 * KP
                + (size_t)(s * CB + w * 32 + n * 16 + (lane & 15)) * KP + ((lane >> 4) << 3);
            #pragma unroll
            for (int kt = 0; kt < 13; ++kt) breg[n][kt] = *(const bf16x8*)(bpp + kt * 32);
        }
        unsigned* hxL = hx + (size_t)(l * NG + g) * HXD * 6400;
        unsigned* ringL = hring + (size_t)(l * NG + g) * RD * 3200;
        const unsigned* zinL = zin + (size_t)((l - 1) * NG + g) * RD * 12800;
        unsigned* FHown = seqb + ((l * NG + g) * NSL + s) * 16;
        const unsigned* FZup = seqb + (60 + ((l - 1) * NG + g) * NSL) * 16;
        const unsigned* FZdn = seqb + (60 + (l * NG + g) * NSL) * 16;

        const int p0 = ((s + 1) % 5) * 80, p1 = ((s + 2) % 5) * 80;
        const int p2 = ((s + 3) % 5) * 80, p3 = ((s + 4) % 5) * 80;
        const int ug0 = s * UB + 2 * up;
        const float pi0 = pp.pi[l][ug0], pi1 = pp.pi[l][ug0 + 1];
        const float pf0 = pp.pf[l][ug0], pf1 = pp.pf[l][ug0 + 1];
        const float po0 = pp.po[l][ug0], po1 = pp.po[l][ug0 + 1];
        float c0 = 0.f, c1 = 0.f;

        __syncthreads();
        if (l == 0 && tid < 16)
            *(uint2*)(&A[tid * AS + 400]) = *(const uint2*)(xpack + ((size_t)0 * 64 + g * 16 + tid) * 4);
        __syncthreads();

        for (int t = 0; t < TSTEPS; ++t) {
            // ---- detect: poll peers' tagged h(t-1) + amortized flag gates ----
            {
                const unsigned want = (unsigned)(t - 1) << 16;
                const unsigned* hb = hxL + (size_t)((t + 3) & 3) * 6400 + er * 400 + 2 * up;
                const unsigned* fp = nullptr; unsigned fneed = 0;
                if (l > 0 && (t & 3) == 0 && tid < NSL) { fp = FZup + tid * 16; fneed = (unsigned)(t + 4); }
                else if (l < 2 && (t & 7) == 0 && tid >= NSL && tid < 2 * NSL) {
                    fp = FZdn + (tid - NSL) * 16; fneed = (unsigned)(t > 8 ? t - 8 : 0);
                }
                unsigned v0, v1, v2, v3, v4, v5, v6, v7;
                for (;;) {
                    bool ok = true;
                    if (t > 0) {
                        v0 = ld_a(hb + p0); v1 = ld_a(hb + p0 + 1);
                        v2 = ld_a(hb + p1); v3 = ld_a(hb + p1 + 1);
                        v4 = ld_a(hb + p2); v5 = ld_a(hb + p2 + 1);
                        v6 = ld_a(hb + p3); v7 = ld_a(hb + p3 + 1);
                        ok = ((v0 & 0xFFFF0000u) == want) & ((v1 & 0xFFFF0000u) == want) &
                             ((v2 & 0xFFFF0000u) == want) & ((v3 & 0xFFFF0000u) == want) &
                             ((v4 & 0xFFFF0000u) == want) & ((v5 & 0xFFFF0000u) == want) &
                             ((v6 & 0xFFFF0000u) == want) & ((v7 & 0xFFFF0000u) == want);
                    }
                    if (fp) ok &= (ld_a(fp) >= fneed);
                    if (__all(ok)) break;
                }
                if (t > 0) {
                    const int ab = er * AS + 2 * up;
                    *(unsigned*)&A[ab + p0] = (v0 & 0xFFFFu) | (v1 << 16);
                    *(unsigned*)&A[ab + p1] = (v2 & 0xFFFFu) | (v3 << 16);
                    *(unsigned*)&A[ab + p2] = (v4 & 0xFFFFu) | (v5 << 16);
                    *(unsigned*)&A[ab + p3] = (v6 & 0xFFFFu) | (v7 << 16);
                }
            }
            __syncthreads();                       // B1 (also drains t-1's global stores)
            if (tid == 0) st_a(FHown, (unsigned)t);   // h(0..t-1) now visible

            unsigned q0, q1, q2, q3;
            if (l > 0) {                           // zin(t) into regs; consumed after B2
                const unsigned* zp = zinL + (size_t)(t & 15) * 12800 + er * 800 + 4 * (s * 40 + up);
                q0 = ld_a(zp); q1 = ld_a(zp + 1); q2 = ld_a(zp + 2); q3 = ld_a(zp + 3);
            }

            floatx4 a0 = {0, 0, 0, 0}, a1 = {0, 0, 0, 0};
            #pragma unroll
            for (int kt = 0; kt < 13; ++kt) {
                bf16x8 a = *(const bf16x8*)(&A[aoff + kt * 32]);
                a0 = __builtin_amdgcn_mfma_f32_16x16x32_bf16(a, breg[0][kt], a0, 0, 0, 0);
                a1 = __builtin_amdgcn_mfma_f32_16x16x32_bf16(a, breg[1][kt], a1, 0, 0, 0);
            }
            #pragma unroll
            for (int ri = 0; ri < 4; ++ri) {
                Z[(zr + ri) * ZS + zc0] = a0[ri];
                Z[(zr + ri) * ZS + zc0 + 16] = a1[ri];
            }
            __syncthreads();                       // B2

            float4 za = *(const float4*)(&Z[er * ZS + 8 * up]);
            float4 zb4 = *(const float4*)(&Z[er * ZS + 8 * up + 4]);
            if (l > 0) {
                za.x += bf_lo(q0); za.y += bf_hi(q0); za.z += bf_lo(q1); za.w += bf_hi(q1);
                zb4.x += bf_lo(q2); zb4.y += bf_hi(q2); zb4.z += bf_lo(q3); zb4.w += bf_hi(q3);
            }
            float iv = sigm_(za.x + pi0 * c0);
            float fv = sigm_(za.y + pf0 * c0);
            float cn = fv * c0 + iv * tanh_(za.z);
            float ov = sigm_(za.w + po0 * cn);
            float h0 = ov * tanh_(cn);
            c0 = cn;
            iv = sigm_(zb4.x + pi1 * c1);
            fv = sigm_(zb4.y + pf1 * c1);
            cn = fv * c1 + iv * tanh_(zb4.z);
            ov = sigm_(zb4.w + po1 * cn);
            float h1 = ov * tanh_(cn);
            c1 = cn;
            unsigned packh = (unsigned)f2bf(h0) | ((unsigned)f2bf(h1) << 16);
            *(unsigned*)&A[er * AS + ug0] = packh;            // own h(t) -> LDS
            if (l == 0 && tid < 16 && t + 1 < TSTEPS)
                *(uint2*)(&A[tid * AS + 400]) = *(const uint2*)(xpack + ((size_t)(t + 1) * 64 + g * 16 + tid) * 4);
            __syncthreads();                       // B3

            // global stores AFTER the barrier: drain hides under next detect
            unsigned* hxs = hxL + (size_t)(t & 3) * 6400 + er * 400 + ug0;
            st_a(hxs, ((unsigned)t << 16) | (packh & 0xFFFFu));
            st_a(hxs + 1, ((unsigned)t << 16) | (packh >> 16));
            if (l < 2)
                st_a(ringL + (size_t)(t & 15) * 3200 + er * 200 + s * 40 + up, packh);
            else
                h2[(size_t)t * 12800 + (g * GB + er) * 200 + s * 40 + up] = packh;
        }
        __syncthreads();
        if (tid == 0) st_a(FHown, (unsigned)TSTEPS);
    } else {
        // ---------------- preGEMM block (TCH=2 steps per iter) ----------------
        const int lz = (idx - 15) / 5;       // feeds layer lz+1
        const int sp = (idx - 15) - lz * 5;
        bf16x8 breg[2][13];
        #pragma unroll
        for (int n = 0; n < 2; ++n) {
            const unsigned short* bpp = Bpre + (size_t)lz * 1600 * KP
                + (size_t)(sp * CB + w * 32 + n * 16 + (lane & 15)) * KP + ((lane >> 4) << 3);
            #pragma unroll
            for (int kt = 0; kt < 13; ++kt) breg[n][kt] = *(const bf16x8*)(bpp + kt * 32);
        }
        const unsigned* ringS = hring + (size_t)(lz * NG + g) * RD * 3200;
        unsigned* zinD = zin + (size_t)(lz * NG + g) * RD * 12800;
        const unsigned* FHup = seqb + ((lz * NG + g) * NSL) * 16;
        const unsigned* FHdn = seqb + (((lz + 1) * NG + g) * NSL) * 16;
        unsigned* FZown = seqb + (60 + (lz * NG + g) * NSL + sp) * 16;
        __syncthreads();

        for (int c = 0; c < TSTEPS; c += 2) {
            {   // ballot poll: h availability + zin-ring backpressure
                const unsigned* fp = nullptr; unsigned need = 0;
                if (tid < NSL) { fp = FHup + tid * 16; need = (unsigned)(c + 2); }
                else if (tid < 2 * NSL) { fp = FHdn + (tid - NSL) * 16; need = (unsigned)(c > 14 ? c - 14 : 0); }
                bool ok = (fp == nullptr) || (ld_a(fp) >= need);
                while (!__all(ok)) { if (!ok) ok = ld_a(fp) >= need; }
            }
            __syncthreads();                       // B1 (drains prev chunk's zin stores)
            if (tid == 0 && c > 0) st_a(FZown, (unsigned)c);   // zin(0..c-1) visible

            for (int i = tid; i < 6400; i += 640) {   // stage h(c),h(c+1)
                int tc = (i >= 3200) ? 1 : 0;
                int j = i - tc * 3200;
                unsigned v = ld_a(ringS + (size_t)((c + tc) & 15) * 3200 + j);
                int r = j / 200, d = j - r * 200;
                *(unsigned*)&A[(tc * 16 + r) * AS + 2 * d] = v;
            }
            if (tid < 32) {
                int tc = tid >> 4, r = tid & 15;
                *(uint2*)(&A[(tc * 16 + r) * AS + 400]) =
                    *(const uint2*)(xpack + ((size_t)(c + tc) * 64 + g * 16 + r) * 4);
            }
            __syncthreads();                       // B2

            floatx4 a00 = {0,0,0,0}, a01 = {0,0,0,0}, a10 = {0,0,0,0}, a11 = {0,0,0,0};
            #pragma unroll
            for (int kt = 0; kt < 13; ++kt) {
                bf16x8 x0 = *(const bf16x8*)(&A[aoff + kt * 32]);
                bf16x8 x1 = *(const bf16x8*)(&A[aoff + 16 * AS + kt * 32]);
                a00 = __builtin_amdgcn_mfma_f32_16x16x32_bf16(x0, breg[0][kt], a00, 0, 0, 0);
                a01 = __builtin_amdgcn_mfma_f32_16x16x32_bf16(x0, breg[1][kt], a01, 0, 0, 0);
                a10 = __builtin_amdgcn_mfma_f32_16x16x32_bf16(x1, breg[0][kt], a10, 0, 0, 0);
                a11 = __builtin_amdgcn_mfma_f32_16x16x32_bf16(x1, breg[1][kt], a11, 0, 0, 0);
            }
            #pragma unroll
            for (int m = 0; m < 2; ++m) {
                #pragma unroll
                for (int ri = 0; ri < 4; ++ri) {
                    Z[(zr + ri) * ZS + zc0] = (m ? a10[ri] : a00[ri]);
                    Z[(zr + ri) * ZS + zc0 + 16] = (m ? a11[ri] : a01[ri]);
                }
                __syncthreads();                   // Z ready
                float4 za = *(const float4*)(&Z[er * ZS + 8 * up]);
                float4 zbv = *(const float4*)(&Z[er * ZS + 8 * up + 4]);
                unsigned* zg = zinD + (size_t)((c + m) & 15) * 12800 + er * 800 + sp * 160 + 4 * up;
                st_a(zg,     (unsigned)f2bf(za.x) | ((unsigned)f2bf(za.y) << 16));
                st_a(zg + 1, (unsigned)f2bf(za.z) | ((unsigned)f2bf(za.w) << 16));
                st_a(zg + 2, (unsigned)f2bf(zbv.x) | ((unsigned)f2bf(zbv.y) << 16));
                st_a(zg + 3, (unsigned)f2bf(zbv.z) | ((unsigned)f2bf(zbv.w) << 16));
                __syncthreads();                   // pack reads done before Z reuse
            }
        }
        __syncthreads();
        if (tid == 0) st_a(FZown, (unsigned)TSTEPS);
    }
}

// ---- MDN head ------------------------------------------------------------
__global__ __launch_bounds__(256)
void mdn_kernel(const unsigned short* __restrict__ h2,
                const unsigned short* __restrict__ Bm,
                float* __restrict__ out) {
    const int blk = blockIdx.x;
    const int b = blk / 25;
    const int t0 = (blk - b * 25) * 32;
    const int tid = threadIdx.x;
    const int lane = tid & 63;
    const int w = tid >> 6;
    const int m = w & 1, nh = w >> 1;

    __shared__ unsigned short A[32 * 424];
    __shared__ float Z[32 * 132];
    __shared__ float rmax[32], rinv[32];

    for (int i = tid; i < 32 * 424; i += 256) A[i] = 0;
    __syncthreads();
    for (int c = tid; c < 32 * 50; c += 256) {
        int r = c / 50, j = c - r * 50;
        *(bf16x8*)(&A[r * 424 + j * 8]) = *(const bf16x8*)(h2 + (size_t)(t0 + r) * 25600 + b * 400 + j * 8);
    }
    if (tid < 32) A[tid * 424 + 400] = 0x3F80u;
    __syncthreads();

    floatx4 acc[4] = {{0,0,0,0},{0,0,0,0},{0,0,0,0},{0,0,0,0}};
    const int aoff = (m * 16 + (lane & 15)) * 424 + ((lane >> 4) << 3);
    #pragma unroll
    for (int kt = 0; kt < 13; ++kt) {
        bf16x8 a = *(const bf16x8*)(&A[aoff + kt * 32]);
        #pragma unroll
        for (int n = 0; n < 4; ++n) {
            const unsigned short* bp = Bm + (size_t)((nh * 4 + n) * 16 + (lane & 15)) * KP
                                          + ((lane >> 4) << 3) + kt * 32;
            acc[n] = __builtin_amdgcn_mfma_f32_16x16x32_bf16(a, *(const bf16x8*)bp, acc[n], 0, 0, 0);
        }
    }
    #pragma unroll
    for (int n = 0; n < 4; ++n) {
        int zc = (nh * 4 + n) * 16 + (lane & 15);
        int zrow = m * 16 + ((lane >> 4) << 2);
        #pragma unroll
        for (int ri = 0; ri < 4; ++ri)
            Z[(zrow + ri) * 132 + zc] = acc[n][ri];
    }
    __syncthreads();
    if (tid < 32) {
        float mx = -1e30f;
        for (int j = 0; j < 20; ++j) mx = fmaxf(mx, Z[tid * 132 + j]);
        float sm = 0.f;
        for (int j = 0; j < 20; ++j) sm += __expf(Z[tid * 132 + j] - mx);
        rmax[tid] = mx;
        rinv[tid] = 1.f / sm;
    }
    __syncthreads();
    for (int idxo = tid; idxo < 32 * 121; idxo += 256) {
        int r = idxo / 121, jo = idxo - r * 121;
        float v = Z[r * 132 + jo];
        float o;
        if (jo < 20) o = __expf(v - rmax[r]) * rinv[r];
        else if (jo < 60) o = v;
        else if (jo < 100) o = __expf(v);
        else if (jo < 120) o = tanh_(v);
        else o = sigm_(v);
        out[(size_t)(b * TSTEPS + t0 + r) * 121 + jo] = o;
    }
}

extern "C" void kernel_launch(void* const* d_in, const int* in_sizes, int n_in,
                              void* d_out, int out_size, void* d_ws, size_t ws_size,
                              hipStream_t stream) {
    const float* x = (const float*)d_in[0];
    const float* Wx[3] = {(const float*)d_in[1], (const float*)d_in[7], (const float*)d_in[13]};
    const float* Wh[3] = {(const float*)d_in[2], (const float*)d_in[8], (const float*)d_in[14]};
    const float* bb[3] = {(const float*)d_in[3], (const float*)d_in[9], (const float*)d_in[15]};
    Peeps pp;
    for (int l = 0; l < 3; ++l) {
        pp.pi[l] = (const float*)d_in[4 + 6 * l];
        pp.pf[l] = (const float*)d_in[5 + 6 * l];
        pp.po[l] = (const float*)d_in[6 + 6 * l];
    }
    const float* Wm = (const float*)d_in[19];
    const float* bm = (const float*)d_in[20];
    float* out = (float*)d_out;

    char* base = (char*)d_ws;
    size_t off = 0;
    auto alloc = [&](size_t bytes) -> void* {
        void* r = base + off;
        off = (off + bytes + 255) & ~(size_t)255;
        return r;
    };
    unsigned* seqb        = (unsigned*)alloc(1600 * sizeof(unsigned));              // 6.4 KB
    unsigned* hx          = (unsigned*)alloc((size_t)3 * NG * HXD * 6400 * 4);      // 1.23 MB
    unsigned* hring       = (unsigned*)alloc((size_t)3 * NG * RD * 3200 * 4);       // 2.46 MB
    unsigned* zin         = (unsigned*)alloc((size_t)2 * NG * RD * 12800 * 4);      // 6.55 MB
    unsigned short* Bp    = (unsigned short*)alloc((size_t)3 * 1600 * KP * 2);      // 4.0 MB
    unsigned short* Bpre  = (unsigned short*)alloc((size_t)2 * 1600 * KP * 2);      // 2.7 MB
    unsigned short* Bm    = (unsigned short*)alloc((size_t)128 * KP * 2);
    unsigned short* xpk   = (unsigned short*)alloc((size_t)TSTEPS * 64 * 4 * 2);
    unsigned short* h2    = (unsigned short*)alloc((size_t)TSTEPS * 64 * 400 * 2);  // 41 MB

    hipMemsetAsync(seqb, 0, 1600 * sizeof(unsigned), stream);
    hipMemsetAsync(hx, 0xAA, (size_t)3 * NG * HXD * 6400 * 4, stream);  // tags can't alias

    for (int l = 0; l < 3; ++l)
        pack_rec<<<2600, 256, 0, stream>>>(Wx[l], Wh[l], bb[l], Bp + (size_t)l * 1600 * KP, l == 0);
    pack_pre<<<2600, 256, 0, stream>>>(Wx[1], bb[1], Bpre);
    pack_pre<<<2600, 256, 0, stream>>>(Wx[2], bb[2], Bpre + (size_t)1600 * KP);
    pack_x<<<200, 256, 0, stream>>>(x, xpk);
    pack_mdn<<<208, 256, 0, stream>>>(Wm, bm, Bm);

    fused_scan<<<200, 640, 0, stream>>>(Bp, Bpre, xpk, hx, hring, zin, seqb,
                                        (unsigned*)h2, pp);

    mdn_kernel<<<1600, 256, 0, stream>>>(h2, Bm, out);
}

// Round 10
// 3037.697 us; speedup vs baseline: 3.6512x; 1.0755x over previous
//
#include <hip/hip_runtime.h>

// DeepHandwritingPredictionModel: 3-layer peephole LSTM (B=64,T=800,U=400) + MDN(M=20)
// Round 10 = Round 4 body + per-(l,g) XCD clustering at 1 block/CU.
//   Grid 120: xcd=bid&7, slot=bid>>3.
//   xcd g in 0..3 : slots 0-4 rec(l=0,g), 5-9 rec(l=2,g), 10-14 pre(lz=1,g)
//   xcd 4+g       : slots 0-4 rec(l=1,g), 5-9 pre(lz=0,g), 10-14 idle
//   The latency-critical hx cycle (5 rec blocks of one layer) is XCD-local;
//   zin consumption is XCD-local; feed-forward paths (hring, flags) may cross
//   XCDs but have multi-step slack. 10-15 blocks/XCD => 1 block/CU (no round-9
//   compute-density serialization). Agent-scope atomics => mapping affects only
//   latency, never correctness.

#define TSTEPS 800
#define NG 4            // batch groups
#define GB 16           // batches per group
#define NSL 5           // slices / splits per (layer,group)
#define UB 80           // units per slice
#define CB 320          // cols per slice (4 gates * UB)
#define KP 416          // padded K (400 h | 3 x | 1 one | pad)
#define RD 16           // hring / zin ring depth
#define HXD 4           // tagged hx ring depth
#define AS 424          // A LDS stride (bf16)
#define ZS 332          // Z LDS stride (f32)

typedef __attribute__((ext_vector_type(8))) __bf16 bf16x8;
typedef __attribute__((ext_vector_type(4))) float floatx4;

struct Peeps { const float* pi[3]; const float* pf[3]; const float* po[3]; };

__device__ __forceinline__ unsigned short f2bf(float f) {
    unsigned int u = __float_as_uint(f);
    return (unsigned short)((u + 0x7FFFu + ((u >> 16) & 1u)) >> 16);
}
__device__ __forceinline__ float bf_lo(unsigned u) { return __uint_as_float(u << 16); }
__device__ __forceinline__ float bf_hi(unsigned u) { return __uint_as_float(u & 0xFFFF0000u); }
__device__ __forceinline__ float sigm_(float v) { return 1.f / (1.f + __expf(-v)); }
__device__ __forceinline__ float tanh_(float v) { float e = __expf(2.f * v); return 1.f - 2.f / (e + 1.f); }
__device__ __forceinline__ unsigned ld_a(const unsigned* p) {
    return __hip_atomic_load(p, __ATOMIC_RELAXED, __HIP_MEMORY_SCOPE_AGENT);
}
__device__ __forceinline__ void st_a(unsigned* p, unsigned v) {
    __hip_atomic_store(p, v, __ATOMIC_RELAXED, __HIP_MEMORY_SCOPE_AGENT);
}

// ---- weight packing ------------------------------------------------------
__global__ void pack_rec(const float* __restrict__ Wx, const float* __restrict__ Wh,
                         const float* __restrict__ bias, unsigned short* __restrict__ dst,
                         int is_l0) {
    int idx = blockIdx.x * 256 + threadIdx.x;
    if (idx >= 1600 * KP) return;
    int col = idx / KP, k = idx - col * KP;
    int co = (col & 3) * 400 + (col >> 2);
    float v = 0.f;
    if (k < 400) v = Wh[k * 1600 + co];
    else if (is_l0) {
        if (k < 403) v = Wx[(k - 400) * 1600 + co];
        else if (k == 403) v = bias[co];
    }
    dst[idx] = f2bf(v);
}
__global__ void pack_pre(const float* __restrict__ Wx, const float* __restrict__ bias,
                         unsigned short* __restrict__ dst) {
    int idx = blockIdx.x * 256 + threadIdx.x;
    if (idx >= 1600 * KP) return;
    int col = idx / KP, k = idx - col * KP;
    int co = (col & 3) * 400 + (col >> 2);
    float v = 0.f;
    if (k < 400) v = Wx[(3 + k) * 1600 + co];
    else if (k < 403) v = Wx[(k - 400) * 1600 + co];
    else if (k == 403) v = bias[co];
    dst[idx] = f2bf(v);
}
__global__ void pack_x(const float* __restrict__ x, unsigned short* __restrict__ xp) {
    int idx = blockIdx.x * 256 + threadIdx.x;   // idx = t*64 + b
    if (idx >= TSTEPS * 64) return;
    int t = idx / 64, b = idx - t * 64;
    unsigned short o[4];
    for (int d = 0; d < 3; ++d) o[d] = f2bf(x[(b * TSTEPS + t) * 3 + d]);
    o[3] = 0x3F80u;
    *(uint2*)(xp + (size_t)idx * 4) = *(uint2*)o;
}
__global__ void pack_mdn(const float* __restrict__ Wm, const float* __restrict__ bm,
                         unsigned short* __restrict__ dst) {
    int idx = blockIdx.x * 256 + threadIdx.x;
    if (idx >= 128 * KP) return;
    int col = idx / KP, k = idx - col * KP;
    float v = 0.f;
    if (col < 121) {
        if (k < 400) v = Wm[k * 121 + col];
        else if (k == 400) v = bm[col];
    }
    dst[idx] = f2bf(v);
}

// ---- fused pipeline ------------------------------------------------------
// hx   : [3][NG][HXD][16][400] u32 tagged (t<<16|bf16), slot t&3
// hring: [3][NG][RD][16][200] u32 packed 2xbf16, slot t&15 (for pre)
// zin  : [2][NG][RD][16][800] u32 packed 2xbf16, slot t&15
// seqb : FH[(l*NG+g)*NSL+s]*16 ; FZ at +60*16: [(lz*NG+g)*NSL+sp]*16
__global__ __launch_bounds__(640)
void fused_scan(const unsigned short* __restrict__ Bp,
                const unsigned short* __restrict__ Bpre,
                const unsigned short* __restrict__ xpack,
                unsigned* __restrict__ hx,
                unsigned* __restrict__ hring,
                unsigned* __restrict__ zin,
                unsigned* __restrict__ seqb,
                unsigned* __restrict__ h2,      // [T][64][200] dwords (2xbf16)
                Peeps pp) {
    const int tid = threadIdx.x;
    const int lane = tid & 63;
    const int w = tid >> 6;
    const int bid = blockIdx.x;

    // ---- XCD-local role decode (bid%8 = XCD, validated by r9 FETCH collapse) ----
    const int xcd = bid & 7;
    const int slot = bid >> 3;        // 0..14
    int g, rl = -1, rs = 0, plz = -1, psp = 0;
    if (xcd < 4) {
        g = xcd;
        if (slot < 5)       { rl = 0; rs = slot; }
        else if (slot < 10) { rl = 2; rs = slot - 5; }
        else                { plz = 1; psp = slot - 10; }
    } else {
        g = xcd - 4;
        if (slot < 5)       { rl = 1; rs = slot; }
        else if (slot < 10) { plz = 0; psp = slot - 5; }
        else return;
    }

    __shared__ unsigned short A[32 * AS];
    __shared__ float Z[16 * ZS];

    for (int i = tid; i < 32 * AS; i += 640) A[i] = 0;

    const int er = tid / 40;          // batch row 0..15
    const int up = tid - er * 40;     // unit-pair 0..39
    const int aoff = (lane & 15) * AS + ((lane >> 4) << 3);
    const int zc0 = w * 32 + (lane & 15);
    const int zr = (lane >> 4) << 2;

    if (rl >= 0) {
        // ---------------- recurrence block ----------------
        const int l = rl;
        const int s = rs;
        bf16x8 breg[2][13];
        #pragma unroll
        for (int n = 0; n < 2; ++n) {
            const unsigned short* bpp = Bp + (size_t)l * 1600 * KP
                + (size_t)(s * CB + w * 32 + n * 16 + (lane & 15)) * KP + ((lane >> 4) << 3);
            #pragma unroll
            for (int kt = 0; kt < 13; ++kt) breg[n][kt] = *(const bf16x8*)(bpp + kt * 32);
        }
        unsigned* hxL = hx + (size_t)(l * NG + g) * HXD * 6400;
        unsigned* ringL = hring + (size_t)(l * NG + g) * RD * 3200;
        const unsigned* zinL = zin + (size_t)((l - 1) * NG + g) * RD * 12800;
        unsigned* FHown = seqb + ((l * NG + g) * NSL + s) * 16;
        const unsigned* FZup = seqb + (60 + ((l - 1) * NG + g) * NSL) * 16;
        const unsigned* FZdn = seqb + (60 + (l * NG + g) * NSL) * 16;

        const int p0 = ((s + 1) % 5) * 80, p1 = ((s + 2) % 5) * 80;
        const int p2 = ((s + 3) % 5) * 80, p3 = ((s + 4) % 5) * 80;
        const int ug0 = s * UB + 2 * up;
        const float pi0 = pp.pi[l][ug0], pi1 = pp.pi[l][ug0 + 1];
        const float pf0 = pp.pf[l][ug0], pf1 = pp.pf[l][ug0 + 1];
        const float po0 = pp.po[l][ug0], po1 = pp.po[l][ug0 + 1];
        float c0 = 0.f, c1 = 0.f;

        __syncthreads();
        if (l == 0 && tid < 16)
            *(uint2*)(&A[tid * AS + 400]) = *(const uint2*)(xpack + ((size_t)0 * 64 + g * 16 + tid) * 4);
        __syncthreads();

        for (int t = 0; t < TSTEPS; ++t) {
            // ---- detect: poll peers' tagged h(t-1) + amortized flag gates ----
            {
                const unsigned want = (unsigned)(t - 1) << 16;
                const unsigned* hb = hxL + (size_t)((t + 3) & 3) * 6400 + er * 400 + 2 * up;
                const unsigned* fp = nullptr; unsigned fneed = 0;
                if (l > 0 && (t & 3) == 0 && tid < NSL) { fp = FZup + tid * 16; fneed = (unsigned)(t + 4); }
                else if (l < 2 && (t & 7) == 0 && tid >= NSL && tid < 2 * NSL) {
                    fp = FZdn + (tid - NSL) * 16; fneed = (unsigned)(t > 8 ? t - 8 : 0);
                }
                unsigned v0, v1, v2, v3, v4, v5, v6, v7;
                for (;;) {
                    bool ok = true;
                    if (t > 0) {
                        v0 = ld_a(hb + p0); v1 = ld_a(hb + p0 + 1);
                        v2 = ld_a(hb + p1); v3 = ld_a(hb + p1 + 1);
                        v4 = ld_a(hb + p2); v5 = ld_a(hb + p2 + 1);
                        v6 = ld_a(hb + p3); v7 = ld_a(hb + p3 + 1);
                        ok = ((v0 & 0xFFFF0000u) == want) & ((v1 & 0xFFFF0000u) == want) &
                             ((v2 & 0xFFFF0000u) == want) & ((v3 & 0xFFFF0000u) == want) &
                             ((v4 & 0xFFFF0000u) == want) & ((v5 & 0xFFFF0000u) == want) &
                             ((v6 & 0xFFFF0000u) == want) & ((v7 & 0xFFFF0000u) == want);
                    }
                    if (fp) ok &= (ld_a(fp) >= fneed);
                    if (__all(ok)) break;
                }
                if (t > 0) {
                    const int ab = er * AS + 2 * up;
                    *(unsigned*)&A[ab + p0] = (v0 & 0xFFFFu) | (v1 << 16);
                    *(unsigned*)&A[ab + p1] = (v2 & 0xFFFFu) | (v3 << 16);
                    *(unsigned*)&A[ab + p2] = (v4 & 0xFFFFu) | (v5 << 16);
                    *(unsigned*)&A[ab + p3] = (v6 & 0xFFFFu) | (v7 << 16);
                }
            }
            __syncthreads();                       // B1 (also drains t-1's global stores)
            if (tid == 0) st_a(FHown, (unsigned)t);   // h(0..t-1) now visible

            unsigned q0, q1, q2, q3;
            if (l > 0) {                           // zin(t) into regs; consumed after B2
                const unsigned* zp = zinL + (size_t)(t & 15) * 12800 + er * 800 + 4 * (s * 40 + up);
                q0 = ld_a(zp); q1 = ld_a(zp + 1); q2 = ld_a(zp + 2); q3 = ld_a(zp + 3);
            }

            floatx4 a0 = {0, 0, 0, 0}, a1 = {0, 0, 0, 0};
            #pragma unroll
            for (int kt = 0; kt < 13; ++kt) {
                bf16x8 a = *(const bf16x8*)(&A[aoff + kt * 32]);
                a0 = __builtin_amdgcn_mfma_f32_16x16x32_bf16(a, breg[0][kt], a0, 0, 0, 0);
                a1 = __builtin_amdgcn_mfma_f32_16x16x32_bf16(a, breg[1][kt], a1, 0, 0, 0);
            }
            #pragma unroll
            for (int ri = 0; ri < 4; ++ri) {
                Z[(zr + ri) * ZS + zc0] = a0[ri];
                Z[(zr + ri) * ZS + zc0 + 16] = a1[ri];
            }
            __syncthreads();                       // B2

            float4 za = *(const float4*)(&Z[er * ZS + 8 * up]);
            float4 zb4 = *(const float4*)(&Z[er * ZS + 8 * up + 4]);
            if (l > 0) {
                za.x += bf_lo(q0); za.y += bf_hi(q0); za.z += bf_lo(q1); za.w += bf_hi(q1);
                zb4.x += bf_lo(q2); zb4.y += bf_hi(q2); zb4.z += bf_lo(q3); zb4.w += bf_hi(q3);
            }
            float iv = sigm_(za.x + pi0 * c0);
            float fv = sigm_(za.y + pf0 * c0);
            float cn = fv * c0 + iv * tanh_(za.z);
            float ov = sigm_(za.w + po0 * cn);
            float h0 = ov * tanh_(cn);
            c0 = cn;
            iv = sigm_(zb4.x + pi1 * c1);
            fv = sigm_(zb4.y + pf1 * c1);
            cn = fv * c1 + iv * tanh_(zb4.z);
            ov = sigm_(zb4.w + po1 * cn);
            float h1 = ov * tanh_(cn);
            c1 = cn;
            unsigned packh = (unsigned)f2bf(h0) | ((unsigned)f2bf(h1) << 16);
            *(unsigned*)&A[er * AS + ug0] = packh;            // own h(t) -> LDS
            if (l == 0 && tid < 16 && t + 1 < TSTEPS)
                *(uint2*)(&A[tid * AS + 400]) = *(const uint2*)(xpack + ((size_t)(t + 1) * 64 + g * 16 + tid) * 4);
            __syncthreads();                       // B3

            // global stores AFTER the barrier: drain hides under next detect
            unsigned* hxs = hxL + (size_t)(t & 3) * 6400 + er * 400 + ug0;
            st_a(hxs, ((unsigned)t << 16) | (packh & 0xFFFFu));
            st_a(hxs + 1, ((unsigned)t << 16) | (packh >> 16));
            if (l < 2)
                st_a(ringL + (size_t)(t & 15) * 3200 + er * 200 + s * 40 + up, packh);
            else
                h2[(size_t)t * 12800 + (g * GB + er) * 200 + s * 40 + up] = packh;
        }
        __syncthreads();
        if (tid == 0) st_a(FHown, (unsigned)TSTEPS);
    } else {
        // ---------------- preGEMM block (TCH=2 steps per iter) ----------------
        const int lz = plz;                  // feeds layer lz+1
        const int sp = psp;
        bf16x8 breg[2][13];
        #pragma unroll
        for (int n = 0; n < 2; ++n) {
            const unsigned short* bpp = Bpre + (size_t)lz * 1600 * KP
                + (size_t)(sp * CB + w * 32 + n * 16 + (lane & 15)) * KP + ((lane >> 4) << 3);
            #pragma unroll
            for (int kt = 0; kt < 13; ++kt) breg[n][kt] = *(const bf16x8*)(bpp + kt * 32);
        }
        const unsigned* ringS = hring + (size_t)(lz * NG + g) * RD * 3200;
        unsigned* zinD = zin + (size_t)(lz * NG + g) * RD * 12800;
        const unsigned* FHup = seqb + ((lz * NG + g) * NSL) * 16;
        const unsigned* FHdn = seqb + (((lz + 1) * NG + g) * NSL) * 16;
        unsigned* FZown = seqb + (60 + (lz * NG + g) * NSL + sp) * 16;
        __syncthreads();

        for (int c = 0; c < TSTEPS; c += 2) {
            {   // ballot poll: h availability + zin-ring backpressure
                const unsigned* fp = nullptr; unsigned need = 0;
                if (tid < NSL) { fp = FHup + tid * 16; need = (unsigned)(c + 2); }
                else if (tid < 2 * NSL) { fp = FHdn + (tid - NSL) * 16; need = (unsigned)(c > 14 ? c - 14 : 0); }
                bool ok = (fp == nullptr) || (ld_a(fp) >= need);
                while (!__all(ok)) { if (!ok) ok = ld_a(fp) >= need; }
            }
            __syncthreads();                       // B1 (drains prev chunk's zin stores)
            if (tid == 0 && c > 0) st_a(FZown, (unsigned)c);   // zin(0..c-1) visible

            for (int i = tid; i < 6400; i += 640) {   // stage h(c),h(c+1)
                int tc = (i >= 3200) ? 1 : 0;
                int j = i - tc * 3200;
                unsigned v = ld_a(ringS + (size_t)((c + tc) & 15) * 3200 + j);
                int r = j / 200, d = j - r * 200;
                *(unsigned*)&A[(tc * 16 + r) * AS + 2 * d] = v;
            }
            if (tid < 32) {
                int tc = tid >> 4, r = tid & 15;
                *(uint2*)(&A[(tc * 16 + r) * AS + 400]) =
                    *(const uint2*)(xpack + ((size_t)(c + tc) * 64 + g * 16 + r) * 4);
            }
            __syncthreads();                       // B2

            floatx4 a00 = {0,0,0,0}, a01 = {0,0,0,0}, a10 = {0,0,0,0}, a11 = {0,0,0,0};
            #pragma unroll
            for (int kt = 0; kt < 13; ++kt) {
                bf16x8 x0 = *(const bf16x8*)(&A[aoff + kt * 32]);
                bf16x8 x1 = *(const bf16x8*)(&A[aoff + 16 * AS + kt * 32]);
                a00 = __builtin_amdgcn_mfma_f32_16x16x32_bf16(x0, breg[0][kt], a00, 0, 0, 0);
                a01 = __builtin_amdgcn_mfma_f32_16x16x32_bf16(x0, breg[1][kt], a01, 0, 0, 0);
                a10 = __builtin_amdgcn_mfma_f32_16x16x32_bf16(x1, breg[0][kt], a10, 0, 0, 0);
                a11 = __builtin_amdgcn_mfma_f32_16x16x32_bf16(x1, breg[1][kt], a11, 0, 0, 0);
            }
            #pragma unroll
            for (int m = 0; m < 2; ++m) {
                #pragma unroll
                for (int ri = 0; ri < 4; ++ri) {
                    Z[(zr + ri) * ZS + zc0] = (m ? a10[ri] : a00[ri]);
                    Z[(zr + ri) * ZS + zc0 + 16] = (m ? a11[ri] : a01[ri]);
                }
                __syncthreads();                   // Z ready
                float4 za = *(const float4*)(&Z[er * ZS + 8 * up]);
                float4 zbv = *(const float4*)(&Z[er * ZS + 8 * up + 4]);
                unsigned* zg = zinD + (size_t)((c + m) & 15) * 12800 + er * 800 + sp * 160 + 4 * up;
                st_a(zg,     (unsigned)f2bf(za.x) | ((unsigned)f2bf(za.y) << 16));
                st_a(zg + 1, (unsigned)f2bf(za.z) | ((unsigned)f2bf(za.w) << 16));
                st_a(zg + 2, (unsigned)f2bf(zbv.x) | ((unsigned)f2bf(zbv.y) << 16));
                st_a(zg + 3, (unsigned)f2bf(zbv.z) | ((unsigned)f2bf(zbv.w) << 16));
                __syncthreads();                   // pack reads done before Z reuse
            }
        }
        __syncthreads();
        if (tid == 0) st_a(FZown, (unsigned)TSTEPS);
    }
}

// ---- MDN head ------------------------------------------------------------
__global__ __launch_bounds__(256)
void mdn_kernel(const unsigned short* __restrict__ h2,
                const unsigned short* __restrict__ Bm,
                float* __restrict__ out) {
    const int blk = blockIdx.x;
    const int b = blk / 25;
    const int t0 = (blk - b * 25) * 32;
    const int tid = threadIdx.x;
    const int lane = tid & 63;
    const int w = tid >> 6;
    const int m = w & 1, nh = w >> 1;

    __shared__ unsigned short A[32 * 424];
    __shared__ float Z[32 * 132];
    __shared__ float rmax[32], rinv[32];

    for (int i = tid; i < 32 * 424; i += 256) A[i] = 0;
    __syncthreads();
    for (int c = tid; c < 32 * 50; c += 256) {
        int r = c / 50, j = c - r * 50;
        *(bf16x8*)(&A[r * 424 + j * 8]) = *(const bf16x8*)(h2 + (size_t)(t0 + r) * 25600 + b * 400 + j * 8);
    }
    if (tid < 32) A[tid * 424 + 400] = 0x3F80u;
    __syncthreads();

    floatx4 acc[4] = {{0,0,0,0},{0,0,0,0},{0,0,0,0},{0,0,0,0}};
    const int aoff = (m * 16 + (lane & 15)) * 424 + ((lane >> 4) << 3);
    #pragma unroll
    for (int kt = 0; kt < 13; ++kt) {
        bf16x8 a = *(const bf16x8*)(&A[aoff + kt * 32]);
        #pragma unroll
        for (int n = 0; n < 4; ++n) {
            const unsigned short* bp = Bm + (size_t)((nh * 4 + n) * 16 + (lane & 15)) * KP
                                          + ((lane >> 4) << 3) + kt * 32;
            acc[n] = __builtin_amdgcn_mfma_f32_16x16x32_bf16(a, *(const bf16x8*)bp, acc[n], 0, 0, 0);
        }
    }
    #pragma unroll
    for (int n = 0; n < 4; ++n) {
        int zc = (nh * 4 + n) * 16 + (lane & 15);
        int zrow = m * 16 + ((lane >> 4) << 2);
        #pragma unroll
        for (int ri = 0; ri < 4; ++ri)
            Z[(zrow + ri) * 132 + zc] = acc[n][ri];
    }
    __syncthreads();
    if (tid < 32) {
        float mx = -1e30f;
        for (int j = 0; j < 20; ++j) mx = fmaxf(mx, Z[tid * 132 + j]);
        float sm = 0.f;
        for (int j = 0; j < 20; ++j) sm += __expf(Z[tid * 132 + j] - mx);
        rmax[tid] = mx;
        rinv[tid] = 1.f / sm;
    }
    __syncthreads();
    for (int idxo = tid; idxo < 32 * 121; idxo += 256) {
        int r = idxo / 121, jo = idxo - r * 121;
        float v = Z[r * 132 + jo];
        float o;
        if (jo < 20) o = __expf(v - rmax[r]) * rinv[r];
        else if (jo < 60) o = v;
        else if (jo < 100) o = __expf(v);
        else if (jo < 120) o = tanh_(v);
        else o = sigm_(v);
        out[(size_t)(b * TSTEPS + t0 + r) * 121 + jo] = o;
    }
}

extern "C" void kernel_launch(void* const* d_in, const int* in_sizes, int n_in,
                              void* d_out, int out_size, void* d_ws, size_t ws_size,
                              hipStream_t stream) {
    const float* x = (const float*)d_in[0];
    const float* Wx[3] = {(const float*)d_in[1], (const float*)d_in[7], (const float*)d_in[13]};
    const float* Wh[3] = {(const float*)d_in[2], (const float*)d_in[8], (const float*)d_in[14]};
    const float* bb[3] = {(const float*)d_in[3], (const float*)d_in[9], (const float*)d_in[15]};
    Peeps pp;
    for (int l = 0; l < 3; ++l) {
        pp.pi[l] = (const float*)d_in[4 + 6 * l];
        pp.pf[l] = (const float*)d_in[5 + 6 * l];
        pp.po[l] = (const float*)d_in[6 + 6 * l];
    }
    const float* Wm = (const float*)d_in[19];
    const float* bm = (const float*)d_in[20];
    float* out = (float*)d_out;

    char* base = (char*)d_ws;
    size_t off = 0;
    auto alloc = [&](size_t bytes) -> void* {
        void* r = base + off;
        off = (off + bytes + 255) & ~(size_t)255;
        return r;
    };
    unsigned* seqb        = (unsigned*)alloc(1600 * sizeof(unsigned));              // 6.4 KB
    unsigned* hx          = (unsigned*)alloc((size_t)3 * NG * HXD * 6400 * 4);      // 1.23 MB
    unsigned* hring       = (unsigned*)alloc((size_t)3 * NG * RD * 3200 * 4);       // 2.46 MB
    unsigned* zin         = (unsigned*)alloc((size_t)2 * NG * RD * 12800 * 4);      // 6.55 MB
    unsigned short* Bp    = (unsigned short*)alloc((size_t)3 * 1600 * KP * 2);      // 4.0 MB
    unsigned short* Bpre  = (unsigned short*)alloc((size_t)2 * 1600 * KP * 2);      // 2.7 MB
    unsigned short* Bm    = (unsigned short*)alloc((size_t)128 * KP * 2);
    unsigned short* xpk   = (unsigned short*)alloc((size_t)TSTEPS * 64 * 4 * 2);
    unsigned short* h2    = (unsigned short*)alloc((size_t)TSTEPS * 64 * 400 * 2);  // 41 MB

    hipMemsetAsync(seqb, 0, 1600 * sizeof(unsigned), stream);
    hipMemsetAsync(hx, 0xAA, (size_t)3 * NG * HXD * 6400 * 4, stream);  // tags can't alias

    for (int l = 0; l < 3; ++l)
        pack_rec<<<2600, 256, 0, stream>>>(Wx[l], Wh[l], bb[l], Bp + (size_t)l * 1600 * KP, l == 0);
    pack_pre<<<2600, 256, 0, stream>>>(Wx[1], bb[1], Bpre);
    pack_pre<<<2600, 256, 0, stream>>>(Wx[2], bb[2], Bpre + (size_t)1600 * KP);
    pack_x<<<200, 256, 0, stream>>>(x, xpk);
    pack_mdn<<<208, 256, 0, stream>>>(Wm, bm, Bm);

    fused_scan<<<120, 640, 0, stream>>>(Bp, Bpre, xpk, hx, hring, zin, seqb,
                                        (unsigned*)h2, pp);

    mdn_kernel<<<1600, 256, 0, stream>>>(h2, Bm, out);
}